// Round 6
// baseline (2470.626 us; speedup 1.0000x reference)
//
#include <hip/hip_runtime.h>
#include <math.h>

// Problem constants (match reference file)
#define NNODES 100000
#define NEDGE  1600000
#define HD     64
#define INDIM  256

#define RB   32                 // rows per bucket
#define NB   3125               // NNODES / RB (exact)
#define NKEY (4 * NB)           // 12500 (a, bucket) regions
#define CAP  1024               // edges per LDS stage chunk (Poisson(512) -> never exceeded)

static constexpr size_t NP = (size_t)NNODES * HD;   // 6.4M floats per [N,H] plane
static constexpr size_t ME = (size_t)4 * NEDGE;     // 6.4M edges total

// workspace layout (floats) — total ~206.6 MB (< 235 MB proven available)
static constexpr size_t XPB_OFF  = 0;                  // uint bf16x2 (x0,x1): NP
static constexpr size_t SPB_OFF  = NP;                 // uint bf16x2 (s1,t1): NP
static constexpr size_t CRES_OFF = 2 * NP;             // s2 accumulator (f32)
static constexpr size_t CZ0_OFF  = 3 * NP;             // z0 (f32)
static constexpr size_t CZ1_OFF  = 4 * NP;             // z1 (f32)
static constexpr size_t EPK_OFF  = 5 * NP;             // int2 (col,val) sorted: 2*ME
static constexpr size_t PERM_OFF = 5 * NP + 2 * ME;    // ME ints
static constexpr size_t CNT_OFF  = PERM_OFF + ME;      // NKEY ints
static constexpr size_t OFF_OFF  = CNT_OFF + NKEY;     // NKEY ints
static constexpr size_t CUR_OFF  = OFF_OFF + NKEY;     // NKEY ints
static constexpr size_t ROFF_OFF = CUR_OFF + NKEY;     // NKEY*RB ints (row offsets)
static constexpr size_t WC_OFF   = ROFF_OFF + (size_t)NKEY * RB;  // 26 floats

// ---------------- helpers ----------------
__device__ __forceinline__ float wave_bsum(float v) {
#pragma unroll
  for (int m = 1; m < 64; m <<= 1) v += __shfl_xor(v, m, 64);
  return v;
}

__device__ __forceinline__ unsigned int bf2pack(float a, float b) {
  unsigned int ua = __float_as_uint(a);
  ua += 0x7FFFu + ((ua >> 16) & 1u);        // RNE
  unsigned int ub = __float_as_uint(b);
  ub += 0x7FFFu + ((ub >> 16) & 1u);
  return (ua >> 16) | (ub & 0xFFFF0000u);
}
__device__ __forceinline__ float bf_lo(unsigned int g) { return __uint_as_float(g << 16); }
__device__ __forceinline__ float bf_hi(unsigned int g) { return __uint_as_float(g & 0xFFFF0000u); }

// ---------------- arch-weight softmax coefficients ----------------
// wc layout:
//  [0..2]   softmax(as_seq0 row0)/3      (s1 from S0[0..2])
//  [3..5]   softmax(as_seq0 row1)/3      (s2 seq part from S1[0..2])
//  [6..9]   softmax(as_res0)/4           (s2 res part from S0[0..3])
//  [10..11] softmax(as_last_seq0)/2      (z0 from S2[0..1])
//  [12..14] softmax(as_last_res0 row0)/3 (z0 from S0[0,1,3])
//  [15..17] softmax(as_last_res0 row1)/3 (z0 from S1[0,1,3])
//  [18..20] softmax(as_seq1)/3           (t1 from T0[0..2])
//  [21..22] softmax(as_last_seq1)/2      (z1 from T1[0..1])
//  [23..25] softmax(as_last_res1)/3      (z1 from T0[0,1,3])
__global__ void wcoef_kernel(const float* __restrict__ s0, const float* __restrict__ ls0,
                             const float* __restrict__ r0, const float* __restrict__ lr0,
                             const float* __restrict__ s1, const float* __restrict__ ls1,
                             const float* __restrict__ lr1, float* __restrict__ wc) {
  if (threadIdx.x != 0 || blockIdx.x != 0) return;
  auto sm2 = [](const float* a, float* o, float sc) {
    float m = fmaxf(a[0], a[1]);
    float e0 = expf(a[0] - m), e1 = expf(a[1] - m);
    float inv = sc / (e0 + e1);
    o[0] = e0 * inv; o[1] = e1 * inv;
  };
  auto sm3 = [](const float* a, float* o, float sc) {
    float m = fmaxf(a[0], fmaxf(a[1], a[2]));
    float e0 = expf(a[0] - m), e1 = expf(a[1] - m), e2 = expf(a[2] - m);
    float inv = sc / (e0 + e1 + e2);
    o[0] = e0 * inv; o[1] = e1 * inv; o[2] = e2 * inv;
  };
  auto sm4 = [](const float* a, float* o, float sc) {
    float m = fmaxf(fmaxf(a[0], a[1]), fmaxf(a[2], a[3]));
    float e0 = expf(a[0] - m), e1 = expf(a[1] - m), e2 = expf(a[2] - m), e3 = expf(a[3] - m);
    float inv = sc / (e0 + e1 + e2 + e3);
    o[0] = e0 * inv; o[1] = e1 * inv; o[2] = e2 * inv; o[3] = e3 * inv;
  };
  sm3(s0,      wc + 0,  1.f / 3.f);
  sm3(s0 + 3,  wc + 3,  1.f / 3.f);
  sm4(r0,      wc + 6,  0.25f);
  sm2(ls0,     wc + 10, 0.5f);
  sm3(lr0,     wc + 12, 1.f / 3.f);
  sm3(lr0 + 3, wc + 15, 1.f / 3.f);
  sm3(s1,      wc + 18, 1.f / 3.f);
  sm2(ls1,     wc + 21, 0.5f);
  sm3(lr1,     wc + 23, 1.f / 3.f);
}

// ---------------- per-node typed projection + both affines -> packed bf16x2 ----------------
__global__ __launch_bounds__(256) void hid_kernel(
    const float* __restrict__ feats, const int* __restrict__ types,
    const float* __restrict__ type_W, const float* __restrict__ type_b,
    const float* __restrict__ W0, const float* __restrict__ b0,
    const float* __restrict__ W1, const float* __restrict__ b1,
    unsigned int* __restrict__ xpb) {
  int wave = threadIdx.x >> 6, lane = threadIdx.x & 63;
  int n = blockIdx.x * 4 + wave;
  if (n >= NNODES) return;
  int t = types[n];
  const float* W = type_W + (size_t)t * INDIM * HD;
  const float* f = feats + (size_t)n * INDIM;
  float f0 = f[lane], f1 = f[64 + lane], f2 = f[128 + lane], f3 = f[192 + lane];
  float acc = type_b[t * HD + lane];
#pragma unroll 8
  for (int k = 0; k < 64; k++) acc = fmaf(__shfl(f0, k, 64), W[(k)*HD + lane], acc);
#pragma unroll 8
  for (int k = 0; k < 64; k++) acc = fmaf(__shfl(f1, k, 64), W[(64 + k) * HD + lane], acc);
#pragma unroll 8
  for (int k = 0; k < 64; k++) acc = fmaf(__shfl(f2, k, 64), W[(128 + k) * HD + lane], acc);
#pragma unroll 8
  for (int k = 0; k < 64; k++) acc = fmaf(__shfl(f3, k, 64), W[(192 + k) * HD + lane], acc);
  float a0 = b0[lane], a1 = b1[lane];
#pragma unroll 8
  for (int j = 0; j < 64; j++) {
    float hv = __shfl(acc, j, 64);
    a0 = fmaf(hv, W0[j * HD + lane], a0);
    a1 = fmaf(hv, W1[j * HD + lane], a1);
  }
  xpb[(size_t)n * HD + lane] = bf2pack(a0, a1);
}

// ================= edge build =================
__global__ __launch_bounds__(256) void histb_kernel(const int* __restrict__ rows,
                                                    int* __restrict__ cnt) {
  __shared__ int h[NB];
  int a = blockIdx.y;
  for (int i = threadIdx.x; i < NB; i += 256) h[i] = 0;
  __syncthreads();
  for (int e = blockIdx.x * 256 + threadIdx.x; e < NEDGE; e += gridDim.x * 256)
    atomicAdd(&h[rows[(size_t)a * NEDGE + e] >> 5], 1);
  __syncthreads();
  for (int i = threadIdx.x; i < NB; i += 256) {
    int v = h[i];
    if (v) atomicAdd(&cnt[a * NB + i], v);
  }
}

__global__ __launch_bounds__(256) void scanb_kernel(const int* __restrict__ cnt,
                                                    int* __restrict__ off,
                                                    int* __restrict__ cur) {
  __shared__ int part[256];
  int t = threadIdx.x;
  const int CH = (NKEY + 255) / 256;  // 49
  int base = t * CH;
  int s = 0;
  for (int i = 0; i < CH; i++) {
    int idx = base + i;
    if (idx < NKEY) s += cnt[idx];
  }
  part[t] = s;
  __syncthreads();
  for (int o = 1; o < 256; o <<= 1) {
    int x = (t >= o) ? part[t - o] : 0;
    __syncthreads();
    part[t] += x;
    __syncthreads();
  }
  int run = part[t] - s;
  for (int i = 0; i < CH; i++) {
    int idx = base + i;
    if (idx < NKEY) {
      int c = cnt[idx];
      off[idx] = run;
      cur[idx] = run;
      run += c;
    }
  }
}

// scatter ONLY the 4-byte edge index into bucket append regions
__global__ __launch_bounds__(256) void binscatter_kernel(
    const int* __restrict__ rows, int* __restrict__ cur, int* __restrict__ perm) {
  int a = blockIdx.y;
  int e = blockIdx.x * 256 + threadIdx.x;
  int r = rows[(size_t)a * NEDGE + e];
  int key = a * NB + (r >> 5);
  int pos = atomicAdd(&cur[key], 1);
  perm[pos] = e;
}

// pack: per bucket, gather (col,val) via perm, counting-sort by local row in LDS,
// write epk coalesced + rofftab (row segment starts)
__global__ __launch_bounds__(256) void pack_kernel(
    const int* __restrict__ rows, const int* __restrict__ cols, const float* __restrict__ vals,
    const int* __restrict__ perm, const int* __restrict__ off, const int* __restrict__ cnt,
    int2* __restrict__ epk, int* __restrict__ rofftab) {
  __shared__ int scol[CAP];
  __shared__ float sv[CAP];
  __shared__ int h[RB], hc[RB];
  int key = blockIdx.x;
  int a = key / NB;
  int base = off[key], n = cnt[key];
  int t = threadIdx.x, wv = t >> 6, lane = t & 63;
  if (t < RB) h[t] = 0;
  __syncthreads();
  if (n <= CAP) {
    int lcol[4]; float lv[4]; int llr[4];
    int cl = 0;
#pragma unroll
    for (int j = 0; j < 4; j++) {
      int i = t + j * 256;
      if (i < n) {
        int e = perm[base + i];
        size_t idx = (size_t)a * NEDGE + e;
        int r = rows[idx];
        lcol[cl] = cols[idx];
        lv[cl] = vals[idx];
        llr[cl] = r & 31;
        cl++;
        atomicAdd(&h[r & 31], 1);
      }
    }
    __syncthreads();
    if (wv == 0) {
      int v = (lane < RB) ? h[lane] : 0;
      int incl = v;
#pragma unroll
      for (int o = 1; o < RB; o <<= 1) {
        int x = __shfl_up(incl, o, 64);
        if (lane >= o) incl += x;
      }
      if (lane < RB) {
        int excl = incl - v;
        hc[lane] = excl;
        rofftab[(size_t)key * RB + lane] = excl;
      }
    }
    __syncthreads();
    for (int j = 0; j < cl; j++) {
      int p = atomicAdd(&hc[llr[j]], 1);
      scol[p] = lcol[j];
      sv[p] = lv[j];
    }
    __syncthreads();
    for (int i = t; i < n; i += 256)
      epk[base + i] = make_int2(scol[i], __float_as_int(sv[i]));
  } else {
    // general fallback (never expected; correctness-preserving for any n)
    for (int i = t; i < n; i += 256) {
      int e = perm[base + i];
      atomicAdd(&h[rows[(size_t)a * NEDGE + e] & 31], 1);
    }
    __syncthreads();
    if (wv == 0) {
      int v = (lane < RB) ? h[lane] : 0;
      int incl = v;
#pragma unroll
      for (int o = 1; o < RB; o <<= 1) {
        int x = __shfl_up(incl, o, 64);
        if (lane >= o) incl += x;
      }
      if (lane < RB) {
        int excl = incl - v;
        hc[lane] = excl;
        rofftab[(size_t)key * RB + lane] = excl;
      }
    }
    __syncthreads();
    for (int i = t; i < n; i += 256) {
      int e = perm[base + i];
      size_t idx = (size_t)a * NEDGE + e;
      int p = atomicAdd(&hc[rows[idx] & 31], 1);
      epk[base + p] = make_int2(cols[idx], __float_as_int(vals[idx]));
    }
  }
}

// ================= SpMM stages: pre-sorted epk, LDS staging, register accumulation =====

// stage 1: gather xpb (bf16 x0,x1); write spb(bf16 s1,t1), cres, cz0, cz1
__global__ __launch_bounds__(256) void st1_kernel(
    const int* __restrict__ off, const int* __restrict__ cnt,
    const int* __restrict__ rofftab, const int2* __restrict__ epk,
    const unsigned int* __restrict__ xpb, const float* __restrict__ wc,
    unsigned int* __restrict__ spb, float* __restrict__ cres,
    float* __restrict__ cz0, float* __restrict__ cz1) {
  __shared__ int scol[CAP];
  __shared__ float sv[CAP];
  __shared__ int ro[RB + 1];
  int b = blockIdx.x, t = threadIdx.x;
  int wv = t >> 6, lane = t & 63;
  float as1[8], at1[8], ares[8], az0[8], az1[8];
#pragma unroll
  for (int r = 0; r < 8; r++) { as1[r] = 0.f; at1[r] = 0.f; ares[r] = 0.f; az0[r] = 0.f; az1[r] = 0.f; }
  for (int a = 0; a < 4; a++) {
    int key = a * NB + b;
    int base = off[key], n = cnt[key];
    float w_s1  = (a < 3) ? wc[a] : 0.f;
    float w_res = wc[6 + a];
    float w_z0  = (a == 3) ? wc[14] : ((a < 2) ? wc[12 + a] : 0.f);
    float w_t1  = (a < 3) ? wc[18 + a] : 0.f;
    float w_z1  = (a == 3) ? wc[25] : ((a < 2) ? wc[23 + a] : 0.f);
    bool lds = (n <= CAP);
    __syncthreads();
    if (t < RB) ro[t] = rofftab[(size_t)key * RB + t];
    if (t == RB) ro[RB] = n;
    if (lds) {
      for (int i = t; i < n; i += 256) {
        int2 p = epk[base + i];
        scol[i] = p.x;
        sv[i] = __int_as_float(p.y);
      }
    }
    __syncthreads();
#pragma unroll
    for (int r8 = 0; r8 < 8; r8++) {
      int r = wv * 8 + r8;
      int s0 = ro[r], e0 = ro[r + 1];
      float accs = 0.f, acct = 0.f;
      if (lds) {
        int i = s0;
        for (; i + 1 < e0; i += 2) {
          int c0 = scol[i], c1 = scol[i + 1];
          float v0 = sv[i], v1 = sv[i + 1];
          unsigned int g0 = xpb[(size_t)c0 * 64 + lane];
          unsigned int g1 = xpb[(size_t)c1 * 64 + lane];
          accs = fmaf(v0, bf_lo(g0), accs); acct = fmaf(v0, bf_hi(g0), acct);
          accs = fmaf(v1, bf_lo(g1), accs); acct = fmaf(v1, bf_hi(g1), acct);
        }
        if (i < e0) {
          unsigned int g0 = xpb[(size_t)scol[i] * 64 + lane];
          accs = fmaf(sv[i], bf_lo(g0), accs); acct = fmaf(sv[i], bf_hi(g0), acct);
        }
      } else {
        for (int i = s0; i < e0; i++) {
          int2 p = epk[base + i];
          unsigned int g0 = xpb[(size_t)p.x * 64 + lane];
          float v0 = __int_as_float(p.y);
          accs = fmaf(v0, bf_lo(g0), accs); acct = fmaf(v0, bf_hi(g0), acct);
        }
      }
      as1[r8]  = fmaf(w_s1, accs, as1[r8]);
      ares[r8] = fmaf(w_res, accs, ares[r8]);
      az0[r8]  = fmaf(w_z0, accs, az0[r8]);
      at1[r8]  = fmaf(w_t1, acct, at1[r8]);
      az1[r8]  = fmaf(w_z1, acct, az1[r8]);
    }
  }
  int rowbase = b * RB + wv * 8;
#pragma unroll
  for (int r8 = 0; r8 < 8; r8++) {
    size_t o = (size_t)(rowbase + r8) * 64 + lane;
    spb[o] = bf2pack(as1[r8], at1[r8]);
    cres[o] = ares[r8];
    cz0[o] = az0[r8];
    cz1[o] = az1[r8];
  }
}

// stage 2: gather spb (bf16 s1,t1); add into cres (s2 seq), cz0, cz1
__global__ __launch_bounds__(256) void st2_kernel(
    const int* __restrict__ off, const int* __restrict__ cnt,
    const int* __restrict__ rofftab, const int2* __restrict__ epk,
    const unsigned int* __restrict__ spb, const float* __restrict__ wc,
    float* __restrict__ cres, float* __restrict__ cz0, float* __restrict__ cz1) {
  __shared__ int scol[CAP];
  __shared__ float sv[CAP];
  __shared__ int ro[RB + 1];
  int b = blockIdx.x, t = threadIdx.x;
  int wv = t >> 6, lane = t & 63;
  float dres[8], dz0[8], dz1[8];
#pragma unroll
  for (int r = 0; r < 8; r++) { dres[r] = 0.f; dz0[r] = 0.f; dz1[r] = 0.f; }
  for (int a = 0; a < 4; a++) {
    int key = a * NB + b;
    int base = off[key], n = cnt[key];
    float w_seq = (a < 3) ? wc[3 + a] : 0.f;
    float w_z0  = (a == 3) ? wc[17] : ((a < 2) ? wc[15 + a] : 0.f);
    float w_z1  = (a < 2) ? wc[21 + a] : 0.f;
    bool lds = (n <= CAP);
    __syncthreads();
    if (t < RB) ro[t] = rofftab[(size_t)key * RB + t];
    if (t == RB) ro[RB] = n;
    if (lds) {
      for (int i = t; i < n; i += 256) {
        int2 p = epk[base + i];
        scol[i] = p.x;
        sv[i] = __int_as_float(p.y);
      }
    }
    __syncthreads();
#pragma unroll
    for (int r8 = 0; r8 < 8; r8++) {
      int r = wv * 8 + r8;
      int s0 = ro[r], e0 = ro[r + 1];
      float accs = 0.f, acct = 0.f;
      if (lds) {
        int i = s0;
        for (; i + 1 < e0; i += 2) {
          int c0 = scol[i], c1 = scol[i + 1];
          float v0 = sv[i], v1 = sv[i + 1];
          unsigned int g0 = spb[(size_t)c0 * 64 + lane];
          unsigned int g1 = spb[(size_t)c1 * 64 + lane];
          accs = fmaf(v0, bf_lo(g0), accs); acct = fmaf(v0, bf_hi(g0), acct);
          accs = fmaf(v1, bf_lo(g1), accs); acct = fmaf(v1, bf_hi(g1), acct);
        }
        if (i < e0) {
          unsigned int g0 = spb[(size_t)scol[i] * 64 + lane];
          accs = fmaf(sv[i], bf_lo(g0), accs); acct = fmaf(sv[i], bf_hi(g0), acct);
        }
      } else {
        for (int i = s0; i < e0; i++) {
          int2 p = epk[base + i];
          unsigned int g0 = spb[(size_t)p.x * 64 + lane];
          float v0 = __int_as_float(p.y);
          accs = fmaf(v0, bf_lo(g0), accs); acct = fmaf(v0, bf_hi(g0), acct);
        }
      }
      dres[r8] = fmaf(w_seq, accs, dres[r8]);
      dz0[r8]  = fmaf(w_z0, accs, dz0[r8]);
      dz1[r8]  = fmaf(w_z1, acct, dz1[r8]);
    }
  }
  int rowbase = b * RB + wv * 8;
#pragma unroll
  for (int r8 = 0; r8 < 8; r8++) {
    size_t o = (size_t)(rowbase + r8) * 64 + lane;
    cres[o] += dres[r8];
    cz0[o] += dz0[r8];
    cz1[o] += dz1[r8];
  }
}

// stage 3: gather s2 (=cres, f32) on adjs 0,1 (weight folded); add into cz0
__global__ __launch_bounds__(256) void st3_kernel(
    const int* __restrict__ off, const int* __restrict__ cnt,
    const int* __restrict__ rofftab, const int2* __restrict__ epk,
    const float* __restrict__ s2, const float* __restrict__ wc, float* __restrict__ cz0) {
  __shared__ int scol[CAP];
  __shared__ float sv[CAP];
  __shared__ int ro[RB + 1];
  int b = blockIdx.x, t = threadIdx.x;
  int wv = t >> 6, lane = t & 63;
  float dz[8];
#pragma unroll
  for (int r = 0; r < 8; r++) dz[r] = 0.f;
  for (int a = 0; a < 2; a++) {
    int key = a * NB + b;
    int base = off[key], n = cnt[key];
    float w = wc[10 + a];
    bool lds = (n <= CAP);
    __syncthreads();
    if (t < RB) ro[t] = rofftab[(size_t)key * RB + t];
    if (t == RB) ro[RB] = n;
    if (lds) {
      for (int i = t; i < n; i += 256) {
        int2 p = epk[base + i];
        scol[i] = p.x;
        sv[i] = __int_as_float(p.y);
      }
    }
    __syncthreads();
#pragma unroll
    for (int r8 = 0; r8 < 8; r8++) {
      int r = wv * 8 + r8;
      int s0 = ro[r], e0 = ro[r + 1];
      float accs = 0.f;
      if (lds) {
        int i = s0;
        for (; i + 1 < e0; i += 2) {
          accs = fmaf(sv[i], s2[(size_t)scol[i] * 64 + lane], accs);
          accs = fmaf(sv[i + 1], s2[(size_t)scol[i + 1] * 64 + lane], accs);
        }
        if (i < e0) accs = fmaf(sv[i], s2[(size_t)scol[i] * 64 + lane], accs);
      } else {
        for (int i = s0; i < e0; i++) {
          int2 p = epk[base + i];
          accs = fmaf(__int_as_float(p.y), s2[(size_t)p.x * 64 + lane], accs);
        }
      }
      dz[r8] = fmaf(w, accs, dz[r8]);
    }
  }
  int rowbase = b * RB + wv * 8;
#pragma unroll
  for (int r8 = 0; r8 < 8; r8++) {
    size_t o = (size_t)(rowbase + r8) * 64 + lane;
    cz0[o] += dz[r8];
  }
}

// ---------------- final: LN+gelu both cells, semantic attention, classifier ----------------
__global__ __launch_bounds__(256) void final_kernel(
    const float* __restrict__ cz0, const float* __restrict__ cz1,
    const float* __restrict__ attn1_W, const float* __restrict__ attn1_b,
    const float* __restrict__ attn2_W, const float* __restrict__ attn2_b,
    const float* __restrict__ cls_W, const float* __restrict__ cls_b,
    float* __restrict__ out) {
  int wave = threadIdx.x >> 6, lane = threadIdx.x & 63;
  int n = blockIdx.x * 4 + wave;
  if (n >= NNODES) return;
  size_t idx = (size_t)n * HD + lane;

  float z0 = cz0[idx];
  float z1 = cz1[idx];

  float m0 = wave_bsum(z0) * (1.f / 64.f);
  float dv0 = z0 - m0;
  float var0 = wave_bsum(dv0 * dv0) * (1.f / 64.f);
  float y0 = dv0 * rsqrtf(var0 + 1e-5f);
  float g0 = 0.5f * y0 * (1.f + erff(y0 * 0.70710678118654752f));

  float m1 = wave_bsum(z1) * (1.f / 64.f);
  float dv1 = z1 - m1;
  float var1 = wave_bsum(dv1 * dv1) * (1.f / 64.f);
  float y1 = dv1 * rsqrtf(var1 + 1e-5f);
  float g1 = 0.5f * y1 * (1.f + erff(y1 * 0.70710678118654752f));

  float t0 = attn1_b[lane], t1 = attn1_b[lane];
#pragma unroll 8
  for (int j = 0; j < 64; j++) {
    float w = attn1_W[j * HD + lane];
    t0 = fmaf(__shfl(g0, j, 64), w, t0);
    t1 = fmaf(__shfl(g1, j, 64), w, t1);
  }
  t0 = tanhf(t0);
  t1 = tanhf(t1);
  float aw = attn2_W[lane];
  float a0 = wave_bsum(t0 * aw) + attn2_b[0];
  float a1 = wave_bsum(t1 * aw) + attn2_b[0];
  float mx = fmaxf(a0, a1);
  float e0 = expf(a0 - mx), e1 = expf(a1 - mx);
  float inv = 1.f / (e0 + e1);
  float p0 = e0 * inv, p1 = e1 * inv;
  float o = p0 * g0 + p1 * g1;

#pragma unroll
  for (int k = 0; k < 8; k++) {
    float s = wave_bsum(o * cls_W[lane * 8 + k]);
    if (lane == k) out[(size_t)n * 8 + k] = s + cls_b[k];
  }
}

extern "C" void kernel_launch(void* const* d_in, const int* in_sizes, int n_in,
                              void* d_out, int out_size, void* d_ws, size_t ws_size,
                              hipStream_t stream) {
  const float* node_feats   = (const float*)d_in[0];
  const int*   node_types   = (const int*)d_in[1];
  const int*   adj_rows     = (const int*)d_in[2];
  const int*   adj_cols     = (const int*)d_in[3];
  const float* adj_vals     = (const float*)d_in[4];
  const float* type_W       = (const float*)d_in[5];
  const float* type_b       = (const float*)d_in[6];
  const float* aW0          = (const float*)d_in[7];
  const float* ab0          = (const float*)d_in[8];
  const float* aW1          = (const float*)d_in[9];
  const float* ab1          = (const float*)d_in[10];
  const float* as_seq0      = (const float*)d_in[11];
  const float* as_last_seq0 = (const float*)d_in[12];
  const float* as_res0      = (const float*)d_in[13];
  const float* as_last_res0 = (const float*)d_in[14];
  const float* as_seq1      = (const float*)d_in[15];
  const float* as_last_seq1 = (const float*)d_in[16];
  const float* as_last_res1 = (const float*)d_in[17];
  const float* attn1_W      = (const float*)d_in[18];
  const float* attn1_b      = (const float*)d_in[19];
  const float* attn2_W      = (const float*)d_in[20];
  const float* attn2_b      = (const float*)d_in[21];
  const float* cls_W        = (const float*)d_in[22];
  const float* cls_b        = (const float*)d_in[23];
  float* out = (float*)d_out;
  float* ws = (float*)d_ws;

  unsigned int* xpb = (unsigned int*)(ws + XPB_OFF);
  unsigned int* spb = (unsigned int*)(ws + SPB_OFF);
  float* cres = ws + CRES_OFF;
  float* cz0  = ws + CZ0_OFF;
  float* cz1  = ws + CZ1_OFF;
  int2*  epk  = (int2*)(ws + EPK_OFF);
  int*   perm = (int*)(ws + PERM_OFF);
  int*   cnt  = (int*)(ws + CNT_OFF);
  int*   off  = (int*)(ws + OFF_OFF);
  int*   cur  = (int*)(ws + CUR_OFF);
  int*   roff = (int*)(ws + ROFF_OFF);
  float* wc   = ws + WC_OFF;

  hipMemsetAsync(cnt, 0, NKEY * sizeof(int), stream);

  wcoef_kernel<<<1, 64, 0, stream>>>(as_seq0, as_last_seq0, as_res0, as_last_res0,
                                     as_seq1, as_last_seq1, as_last_res1, wc);

  hid_kernel<<<NNODES / 4, 256, 0, stream>>>(node_feats, node_types, type_W, type_b,
                                             aW0, ab0, aW1, ab1, xpb);

  // edge build: hist -> scan -> perm-scatter (4B) -> pack+sort (coalesced epk write)
  histb_kernel<<<dim3(64, 4), 256, 0, stream>>>(adj_rows, cnt);
  scanb_kernel<<<1, 256, 0, stream>>>(cnt, off, cur);
  binscatter_kernel<<<dim3(NEDGE / 256, 4), 256, 0, stream>>>(adj_rows, cur, perm);
  pack_kernel<<<NKEY, 256, 0, stream>>>(adj_rows, adj_cols, adj_vals, perm, off, cnt,
                                        epk, roff);

  // SpMM stages: pre-sorted edges, register accumulation
  st1_kernel<<<NB, 256, 0, stream>>>(off, cnt, roff, epk, xpb, wc, spb, cres, cz0, cz1);
  st2_kernel<<<NB, 256, 0, stream>>>(off, cnt, roff, epk, spb, wc, cres, cz0, cz1);
  st3_kernel<<<NB, 256, 0, stream>>>(off, cnt, roff, epk, cres, wc, cz0);

  final_kernel<<<NNODES / 4, 256, 0, stream>>>(cz0, cz1,
                                               attn1_W, attn1_b, attn2_W, attn2_b,
                                               cls_W, cls_b, out);
}

// Round 7
// 2036.637 us; speedup vs baseline: 1.2131x; 1.2131x over previous
//
#include <hip/hip_runtime.h>
#include <math.h>

// Problem constants (match reference file)
#define NNODES 100000
#define NEDGE  1600000
#define HD     64
#define INDIM  256

#define RB   32                 // rows per bucket
#define NB   3125               // NNODES / RB (exact)
#define NKEY (4 * NB)           // 12500 (a, bucket) regions
#define CAP  1024               // edges per LDS stage chunk (Poisson(512) -> never exceeded)
#define CHK  64                 // chunks per adjacency (deterministic scatter)
#define EPC  (NEDGE / CHK)      // 25000 edges per chunk

static constexpr size_t NP = (size_t)NNODES * HD;   // 6.4M floats per [N,H] plane
static constexpr size_t ME = (size_t)4 * NEDGE;     // 6.4M edges total
static constexpr int    M2 = NKEY * CHK;            // 800000 (key,chunk) counters
static constexpr int    SCAN1B = (M2 + 1023) / 1024;  // 782

// workspace layout (floats) — total ~212 MB (< 235 MB proven available)
static constexpr size_t XPB_OFF  = 0;                  // uint bf16x2 (x0,x1): NP
static constexpr size_t SPB_OFF  = NP;                 // uint bf16x2 (s1,t1): NP
static constexpr size_t CRES_OFF = 2 * NP;             // s2 accumulator (f32)
static constexpr size_t CZ0_OFF  = 3 * NP;             // z0 (f32)
static constexpr size_t CZ1_OFF  = 4 * NP;             // z1 (f32)
static constexpr size_t EPK_OFF  = 5 * NP;             // int2 (col,val) sorted: 2*ME
static constexpr size_t PERM_OFF = 5 * NP + 2 * ME;    // ME ints
static constexpr size_t CNT2_OFF = PERM_OFF + ME;      // M2 ints  [key][chunk]
static constexpr size_t OFF2_OFF = CNT2_OFF + M2;      // M2 ints
static constexpr size_t PART_OFF = OFF2_OFF + M2;      // 1024 ints
static constexpr size_t OFF_OFF  = PART_OFF + 1024;    // NKEY ints
static constexpr size_t CNTK_OFF = OFF_OFF + NKEY;     // NKEY ints
static constexpr size_t ROFF_OFF = CNTK_OFF + NKEY;    // NKEY*RB ints (row offsets)
static constexpr size_t WC_OFF   = ROFF_OFF + (size_t)NKEY * RB;  // 26 floats

// ---------------- helpers ----------------
__device__ __forceinline__ float wave_bsum(float v) {
#pragma unroll
  for (int m = 1; m < 64; m <<= 1) v += __shfl_xor(v, m, 64);
  return v;
}

__device__ __forceinline__ unsigned int bf2pack(float a, float b) {
  unsigned int ua = __float_as_uint(a);
  ua += 0x7FFFu + ((ua >> 16) & 1u);        // RNE
  unsigned int ub = __float_as_uint(b);
  ub += 0x7FFFu + ((ub >> 16) & 1u);
  return (ua >> 16) | (ub & 0xFFFF0000u);
}
__device__ __forceinline__ float bf_lo(unsigned int g) { return __uint_as_float(g << 16); }
__device__ __forceinline__ float bf_hi(unsigned int g) { return __uint_as_float(g & 0xFFFF0000u); }

// ---------------- arch-weight softmax coefficients ----------------
// wc layout:
//  [0..2]   softmax(as_seq0 row0)/3      (s1 from S0[0..2])
//  [3..5]   softmax(as_seq0 row1)/3      (s2 seq part from S1[0..2])
//  [6..9]   softmax(as_res0)/4           (s2 res part from S0[0..3])
//  [10..11] softmax(as_last_seq0)/2      (z0 from S2[0..1])
//  [12..14] softmax(as_last_res0 row0)/3 (z0 from S0[0,1,3])
//  [15..17] softmax(as_last_res0 row1)/3 (z0 from S1[0,1,3])
//  [18..20] softmax(as_seq1)/3           (t1 from T0[0..2])
//  [21..22] softmax(as_last_seq1)/2      (z1 from T1[0..1])
//  [23..25] softmax(as_last_res1)/3      (z1 from T0[0,1,3])
__global__ void wcoef_kernel(const float* __restrict__ s0, const float* __restrict__ ls0,
                             const float* __restrict__ r0, const float* __restrict__ lr0,
                             const float* __restrict__ s1, const float* __restrict__ ls1,
                             const float* __restrict__ lr1, float* __restrict__ wc) {
  if (threadIdx.x != 0 || blockIdx.x != 0) return;
  auto sm2 = [](const float* a, float* o, float sc) {
    float m = fmaxf(a[0], a[1]);
    float e0 = expf(a[0] - m), e1 = expf(a[1] - m);
    float inv = sc / (e0 + e1);
    o[0] = e0 * inv; o[1] = e1 * inv;
  };
  auto sm3 = [](const float* a, float* o, float sc) {
    float m = fmaxf(a[0], fmaxf(a[1], a[2]));
    float e0 = expf(a[0] - m), e1 = expf(a[1] - m), e2 = expf(a[2] - m);
    float inv = sc / (e0 + e1 + e2);
    o[0] = e0 * inv; o[1] = e1 * inv; o[2] = e2 * inv;
  };
  auto sm4 = [](const float* a, float* o, float sc) {
    float m = fmaxf(fmaxf(a[0], a[1]), fmaxf(a[2], a[3]));
    float e0 = expf(a[0] - m), e1 = expf(a[1] - m), e2 = expf(a[2] - m), e3 = expf(a[3] - m);
    float inv = sc / (e0 + e1 + e2 + e3);
    o[0] = e0 * inv; o[1] = e1 * inv; o[2] = e2 * inv; o[3] = e3 * inv;
  };
  sm3(s0,      wc + 0,  1.f / 3.f);
  sm3(s0 + 3,  wc + 3,  1.f / 3.f);
  sm4(r0,      wc + 6,  0.25f);
  sm2(ls0,     wc + 10, 0.5f);
  sm3(lr0,     wc + 12, 1.f / 3.f);
  sm3(lr0 + 3, wc + 15, 1.f / 3.f);
  sm3(s1,      wc + 18, 1.f / 3.f);
  sm2(ls1,     wc + 21, 0.5f);
  sm3(lr1,     wc + 23, 1.f / 3.f);
}

// ---------------- per-node typed projection + both affines -> packed bf16x2 ----------------
__global__ __launch_bounds__(256) void hid_kernel(
    const float* __restrict__ feats, const int* __restrict__ types,
    const float* __restrict__ type_W, const float* __restrict__ type_b,
    const float* __restrict__ W0, const float* __restrict__ b0,
    const float* __restrict__ W1, const float* __restrict__ b1,
    unsigned int* __restrict__ xpb) {
  int wave = threadIdx.x >> 6, lane = threadIdx.x & 63;
  int n = blockIdx.x * 4 + wave;
  if (n >= NNODES) return;
  int t = types[n];
  const float* W = type_W + (size_t)t * INDIM * HD;
  const float* f = feats + (size_t)n * INDIM;
  float f0 = f[lane], f1 = f[64 + lane], f2 = f[128 + lane], f3 = f[192 + lane];
  float acc = type_b[t * HD + lane];
#pragma unroll 8
  for (int k = 0; k < 64; k++) acc = fmaf(__shfl(f0, k, 64), W[(k)*HD + lane], acc);
#pragma unroll 8
  for (int k = 0; k < 64; k++) acc = fmaf(__shfl(f1, k, 64), W[(64 + k) * HD + lane], acc);
#pragma unroll 8
  for (int k = 0; k < 64; k++) acc = fmaf(__shfl(f2, k, 64), W[(128 + k) * HD + lane], acc);
#pragma unroll 8
  for (int k = 0; k < 64; k++) acc = fmaf(__shfl(f3, k, 64), W[(192 + k) * HD + lane], acc);
  float a0 = b0[lane], a1 = b1[lane];
#pragma unroll 8
  for (int j = 0; j < 64; j++) {
    float hv = __shfl(acc, j, 64);
    a0 = fmaf(hv, W0[j * HD + lane], a0);
    a1 = fmaf(hv, W1[j * HD + lane], a1);
  }
  xpb[(size_t)n * HD + lane] = bf2pack(a0, a1);
}

// ================= deterministic two-pass edge build (no global atomics) =================
// pass 1: per-(adjacency, chunk) LDS histogram over row-buckets -> cnt2[key][chunk]
__global__ __launch_bounds__(256) void histb2_kernel(const int* __restrict__ rows,
                                                     int* __restrict__ cnt2) {
  __shared__ int h[NB];
  int a = blockIdx.y, ch = blockIdx.x;
  for (int i = threadIdx.x; i < NB; i += 256) h[i] = 0;
  __syncthreads();
  int base = ch * EPC;
  for (int e = base + threadIdx.x; e < base + EPC; e += 256)
    atomicAdd(&h[rows[(size_t)a * NEDGE + e] >> 5], 1);
  __syncthreads();
  for (int b = threadIdx.x; b < NB; b += 256)
    cnt2[((size_t)(a * NB + b) << 6) | ch] = h[b];
}

// hierarchical exclusive scan of cnt2 (M2 elements) -> off2
__global__ __launch_bounds__(256) void scan1_kernel(const int* __restrict__ cnt2,
                                                    int* __restrict__ off2,
                                                    int* __restrict__ part) {
  __shared__ int sdata[256];
  int t = threadIdx.x;
  int base = blockIdx.x * 1024 + t * 4;
  int v0 = (base + 0 < M2) ? cnt2[base + 0] : 0;
  int v1 = (base + 1 < M2) ? cnt2[base + 1] : 0;
  int v2 = (base + 2 < M2) ? cnt2[base + 2] : 0;
  int v3 = (base + 3 < M2) ? cnt2[base + 3] : 0;
  int tsum = v0 + v1 + v2 + v3;
  sdata[t] = tsum;
  __syncthreads();
  for (int o = 1; o < 256; o <<= 1) {
    int x = (t >= o) ? sdata[t - o] : 0;
    __syncthreads();
    sdata[t] += x;
    __syncthreads();
  }
  int excl = sdata[t] - tsum;
  if (t == 255) part[blockIdx.x] = sdata[255];
  if (base + 0 < M2) off2[base + 0] = excl;
  if (base + 1 < M2) off2[base + 1] = excl + v0;
  if (base + 2 < M2) off2[base + 2] = excl + v0 + v1;
  if (base + 3 < M2) off2[base + 3] = excl + v0 + v1 + v2;
}

__global__ __launch_bounds__(1024) void scan2_kernel(int* __restrict__ part) {
  __shared__ int sdata[1024];
  int t = threadIdx.x;
  int v = (t < SCAN1B) ? part[t] : 0;
  sdata[t] = v;
  __syncthreads();
  for (int o = 1; o < 1024; o <<= 1) {
    int x = (t >= o) ? sdata[t - o] : 0;
    __syncthreads();
    sdata[t] += x;
    __syncthreads();
  }
  if (t < SCAN1B) part[t] = sdata[t] - v;  // exclusive
}

__global__ __launch_bounds__(256) void scan3_kernel(int* __restrict__ off2,
                                                    const int* __restrict__ part) {
  int p = part[blockIdx.x];
  int t = threadIdx.x;
#pragma unroll
  for (int j = 0; j < 4; j++) {
    int i = blockIdx.x * 1024 + j * 256 + t;
    if (i < M2) off2[i] += p;
  }
}

// per-key base offset + count (for pack and stages)
__global__ __launch_bounds__(256) void keyoff_kernel(const int* __restrict__ off2,
                                                     int* __restrict__ off,
                                                     int* __restrict__ cntk) {
  int k = blockIdx.x * 256 + threadIdx.x;
  if (k >= NKEY) return;
  int s = off2[(size_t)k << 6];
  int e = (k + 1 < NKEY) ? off2[(size_t)(k + 1) << 6] : (int)ME;
  off[k] = s;
  cntk[k] = e - s;
}

// pass 2: deterministic scatter of edge indices using LDS cursors (no global atomics)
__global__ __launch_bounds__(256) void scatterd_kernel(const int* __restrict__ rows,
                                                       const int* __restrict__ off2,
                                                       int* __restrict__ perm) {
  __shared__ int cur[NB];
  int a = blockIdx.y, ch = blockIdx.x;
  for (int b = threadIdx.x; b < NB; b += 256)
    cur[b] = off2[((size_t)(a * NB + b) << 6) | ch];
  __syncthreads();
  int base = ch * EPC;
  for (int e = base + threadIdx.x; e < base + EPC; e += 256) {
    int r = rows[(size_t)a * NEDGE + e];
    int pos = atomicAdd(&cur[r >> 5], 1);
    perm[pos] = e;
  }
}

// pack: per bucket, gather (col,val) via perm, counting-sort by local row in LDS,
// write epk coalesced + rofftab (row segment starts)
__global__ __launch_bounds__(256) void pack_kernel(
    const int* __restrict__ rows, const int* __restrict__ cols, const float* __restrict__ vals,
    const int* __restrict__ perm, const int* __restrict__ off, const int* __restrict__ cnt,
    int2* __restrict__ epk, int* __restrict__ rofftab) {
  __shared__ int scol[CAP];
  __shared__ float sv[CAP];
  __shared__ int h[RB], hc[RB];
  int key = blockIdx.x;
  int a = key / NB;
  int base = off[key], n = cnt[key];
  int t = threadIdx.x, wv = t >> 6, lane = t & 63;
  if (t < RB) h[t] = 0;
  __syncthreads();
  if (n <= CAP) {
    int lcol[4]; float lv[4]; int llr[4];
    int cl = 0;
#pragma unroll
    for (int j = 0; j < 4; j++) {
      int i = t + j * 256;
      if (i < n) {
        int e = perm[base + i];
        size_t idx = (size_t)a * NEDGE + e;
        int r = rows[idx];
        lcol[cl] = cols[idx];
        lv[cl] = vals[idx];
        llr[cl] = r & 31;
        cl++;
        atomicAdd(&h[r & 31], 1);
      }
    }
    __syncthreads();
    if (wv == 0) {
      int v = (lane < RB) ? h[lane] : 0;
      int incl = v;
#pragma unroll
      for (int o = 1; o < RB; o <<= 1) {
        int x = __shfl_up(incl, o, 64);
        if (lane >= o) incl += x;
      }
      if (lane < RB) {
        int excl = incl - v;
        hc[lane] = excl;
        rofftab[(size_t)key * RB + lane] = excl;
      }
    }
    __syncthreads();
    for (int j = 0; j < cl; j++) {
      int p = atomicAdd(&hc[llr[j]], 1);
      scol[p] = lcol[j];
      sv[p] = lv[j];
    }
    __syncthreads();
    for (int i = t; i < n; i += 256)
      epk[base + i] = make_int2(scol[i], __float_as_int(sv[i]));
  } else {
    // general fallback (never expected; correctness-preserving for any n)
    for (int i = t; i < n; i += 256) {
      int e = perm[base + i];
      atomicAdd(&h[rows[(size_t)a * NEDGE + e] & 31], 1);
    }
    __syncthreads();
    if (wv == 0) {
      int v = (lane < RB) ? h[lane] : 0;
      int incl = v;
#pragma unroll
      for (int o = 1; o < RB; o <<= 1) {
        int x = __shfl_up(incl, o, 64);
        if (lane >= o) incl += x;
      }
      if (lane < RB) {
        int excl = incl - v;
        hc[lane] = excl;
        rofftab[(size_t)key * RB + lane] = excl;
      }
    }
    __syncthreads();
    for (int i = t; i < n; i += 256) {
      int e = perm[base + i];
      size_t idx = (size_t)a * NEDGE + e;
      int p = atomicAdd(&hc[rows[idx] & 31], 1);
      epk[base + p] = make_int2(cols[idx], __float_as_int(vals[idx]));
    }
  }
}

// ================= SpMM stages: pre-sorted epk, LDS staging, register accumulation =====

// stage 1: gather xpb (bf16 x0,x1); write spb(bf16 s1,t1), cres, cz0, cz1
__global__ __launch_bounds__(256) void st1_kernel(
    const int* __restrict__ off, const int* __restrict__ cnt,
    const int* __restrict__ rofftab, const int2* __restrict__ epk,
    const unsigned int* __restrict__ xpb, const float* __restrict__ wc,
    unsigned int* __restrict__ spb, float* __restrict__ cres,
    float* __restrict__ cz0, float* __restrict__ cz1) {
  __shared__ int scol[CAP];
  __shared__ float sv[CAP];
  __shared__ int ro[RB + 1];
  int b = blockIdx.x, t = threadIdx.x;
  int wv = t >> 6, lane = t & 63;
  float as1[8], at1[8], ares[8], az0[8], az1[8];
#pragma unroll
  for (int r = 0; r < 8; r++) { as1[r] = 0.f; at1[r] = 0.f; ares[r] = 0.f; az0[r] = 0.f; az1[r] = 0.f; }
  for (int a = 0; a < 4; a++) {
    int key = a * NB + b;
    int base = off[key], n = cnt[key];
    float w_s1  = (a < 3) ? wc[a] : 0.f;
    float w_res = wc[6 + a];
    float w_z0  = (a == 3) ? wc[14] : ((a < 2) ? wc[12 + a] : 0.f);
    float w_t1  = (a < 3) ? wc[18 + a] : 0.f;
    float w_z1  = (a == 3) ? wc[25] : ((a < 2) ? wc[23 + a] : 0.f);
    bool lds = (n <= CAP);
    __syncthreads();
    if (t < RB) ro[t] = rofftab[(size_t)key * RB + t];
    if (t == RB) ro[RB] = n;
    if (lds) {
      for (int i = t; i < n; i += 256) {
        int2 p = epk[base + i];
        scol[i] = p.x;
        sv[i] = __int_as_float(p.y);
      }
    }
    __syncthreads();
#pragma unroll
    for (int r8 = 0; r8 < 8; r8++) {
      int r = wv * 8 + r8;
      int s0 = ro[r], e0 = ro[r + 1];
      float accs = 0.f, acct = 0.f;
      if (lds) {
        int i = s0;
        for (; i + 1 < e0; i += 2) {
          int c0 = scol[i], c1 = scol[i + 1];
          float v0 = sv[i], v1 = sv[i + 1];
          unsigned int g0 = xpb[(size_t)c0 * 64 + lane];
          unsigned int g1 = xpb[(size_t)c1 * 64 + lane];
          accs = fmaf(v0, bf_lo(g0), accs); acct = fmaf(v0, bf_hi(g0), acct);
          accs = fmaf(v1, bf_lo(g1), accs); acct = fmaf(v1, bf_hi(g1), acct);
        }
        if (i < e0) {
          unsigned int g0 = xpb[(size_t)scol[i] * 64 + lane];
          accs = fmaf(sv[i], bf_lo(g0), accs); acct = fmaf(sv[i], bf_hi(g0), acct);
        }
      } else {
        for (int i = s0; i < e0; i++) {
          int2 p = epk[base + i];
          unsigned int g0 = xpb[(size_t)p.x * 64 + lane];
          float v0 = __int_as_float(p.y);
          accs = fmaf(v0, bf_lo(g0), accs); acct = fmaf(v0, bf_hi(g0), acct);
        }
      }
      as1[r8]  = fmaf(w_s1, accs, as1[r8]);
      ares[r8] = fmaf(w_res, accs, ares[r8]);
      az0[r8]  = fmaf(w_z0, accs, az0[r8]);
      at1[r8]  = fmaf(w_t1, acct, at1[r8]);
      az1[r8]  = fmaf(w_z1, acct, az1[r8]);
    }
  }
  int rowbase = b * RB + wv * 8;
#pragma unroll
  for (int r8 = 0; r8 < 8; r8++) {
    size_t o = (size_t)(rowbase + r8) * 64 + lane;
    spb[o] = bf2pack(as1[r8], at1[r8]);
    cres[o] = ares[r8];
    cz0[o] = az0[r8];
    cz1[o] = az1[r8];
  }
}

// stage 2: gather spb (bf16 s1,t1); add into cres (s2 seq), cz0, cz1
__global__ __launch_bounds__(256) void st2_kernel(
    const int* __restrict__ off, const int* __restrict__ cnt,
    const int* __restrict__ rofftab, const int2* __restrict__ epk,
    const unsigned int* __restrict__ spb, const float* __restrict__ wc,
    float* __restrict__ cres, float* __restrict__ cz0, float* __restrict__ cz1) {
  __shared__ int scol[CAP];
  __shared__ float sv[CAP];
  __shared__ int ro[RB + 1];
  int b = blockIdx.x, t = threadIdx.x;
  int wv = t >> 6, lane = t & 63;
  float dres[8], dz0[8], dz1[8];
#pragma unroll
  for (int r = 0; r < 8; r++) { dres[r] = 0.f; dz0[r] = 0.f; dz1[r] = 0.f; }
  for (int a = 0; a < 4; a++) {
    int key = a * NB + b;
    int base = off[key], n = cnt[key];
    float w_seq = (a < 3) ? wc[3 + a] : 0.f;
    float w_z0  = (a == 3) ? wc[17] : ((a < 2) ? wc[15 + a] : 0.f);
    float w_z1  = (a < 2) ? wc[21 + a] : 0.f;
    bool lds = (n <= CAP);
    __syncthreads();
    if (t < RB) ro[t] = rofftab[(size_t)key * RB + t];
    if (t == RB) ro[RB] = n;
    if (lds) {
      for (int i = t; i < n; i += 256) {
        int2 p = epk[base + i];
        scol[i] = p.x;
        sv[i] = __int_as_float(p.y);
      }
    }
    __syncthreads();
#pragma unroll
    for (int r8 = 0; r8 < 8; r8++) {
      int r = wv * 8 + r8;
      int s0 = ro[r], e0 = ro[r + 1];
      float accs = 0.f, acct = 0.f;
      if (lds) {
        int i = s0;
        for (; i + 1 < e0; i += 2) {
          int c0 = scol[i], c1 = scol[i + 1];
          float v0 = sv[i], v1 = sv[i + 1];
          unsigned int g0 = spb[(size_t)c0 * 64 + lane];
          unsigned int g1 = spb[(size_t)c1 * 64 + lane];
          accs = fmaf(v0, bf_lo(g0), accs); acct = fmaf(v0, bf_hi(g0), acct);
          accs = fmaf(v1, bf_lo(g1), accs); acct = fmaf(v1, bf_hi(g1), acct);
        }
        if (i < e0) {
          unsigned int g0 = spb[(size_t)scol[i] * 64 + lane];
          accs = fmaf(sv[i], bf_lo(g0), accs); acct = fmaf(sv[i], bf_hi(g0), acct);
        }
      } else {
        for (int i = s0; i < e0; i++) {
          int2 p = epk[base + i];
          unsigned int g0 = spb[(size_t)p.x * 64 + lane];
          float v0 = __int_as_float(p.y);
          accs = fmaf(v0, bf_lo(g0), accs); acct = fmaf(v0, bf_hi(g0), acct);
        }
      }
      dres[r8] = fmaf(w_seq, accs, dres[r8]);
      dz0[r8]  = fmaf(w_z0, accs, dz0[r8]);
      dz1[r8]  = fmaf(w_z1, acct, dz1[r8]);
    }
  }
  int rowbase = b * RB + wv * 8;
#pragma unroll
  for (int r8 = 0; r8 < 8; r8++) {
    size_t o = (size_t)(rowbase + r8) * 64 + lane;
    cres[o] += dres[r8];
    cz0[o] += dz0[r8];
    cz1[o] += dz1[r8];
  }
}

// stage 3: gather s2 (=cres, f32) on adjs 0,1 (weight folded); add into cz0
__global__ __launch_bounds__(256) void st3_kernel(
    const int* __restrict__ off, const int* __restrict__ cnt,
    const int* __restrict__ rofftab, const int2* __restrict__ epk,
    const float* __restrict__ s2, const float* __restrict__ wc, float* __restrict__ cz0) {
  __shared__ int scol[CAP];
  __shared__ float sv[CAP];
  __shared__ int ro[RB + 1];
  int b = blockIdx.x, t = threadIdx.x;
  int wv = t >> 6, lane = t & 63;
  float dz[8];
#pragma unroll
  for (int r = 0; r < 8; r++) dz[r] = 0.f;
  for (int a = 0; a < 2; a++) {
    int key = a * NB + b;
    int base = off[key], n = cnt[key];
    float w = wc[10 + a];
    bool lds = (n <= CAP);
    __syncthreads();
    if (t < RB) ro[t] = rofftab[(size_t)key * RB + t];
    if (t == RB) ro[RB] = n;
    if (lds) {
      for (int i = t; i < n; i += 256) {
        int2 p = epk[base + i];
        scol[i] = p.x;
        sv[i] = __int_as_float(p.y);
      }
    }
    __syncthreads();
#pragma unroll
    for (int r8 = 0; r8 < 8; r8++) {
      int r = wv * 8 + r8;
      int s0 = ro[r], e0 = ro[r + 1];
      float accs = 0.f;
      if (lds) {
        int i = s0;
        for (; i + 1 < e0; i += 2) {
          accs = fmaf(sv[i], s2[(size_t)scol[i] * 64 + lane], accs);
          accs = fmaf(sv[i + 1], s2[(size_t)scol[i + 1] * 64 + lane], accs);
        }
        if (i < e0) accs = fmaf(sv[i], s2[(size_t)scol[i] * 64 + lane], accs);
      } else {
        for (int i = s0; i < e0; i++) {
          int2 p = epk[base + i];
          accs = fmaf(__int_as_float(p.y), s2[(size_t)p.x * 64 + lane], accs);
        }
      }
      dz[r8] = fmaf(w, accs, dz[r8]);
    }
  }
  int rowbase = b * RB + wv * 8;
#pragma unroll
  for (int r8 = 0; r8 < 8; r8++) {
    size_t o = (size_t)(rowbase + r8) * 64 + lane;
    cz0[o] += dz[r8];
  }
}

// ---------------- final: LN+gelu both cells, semantic attention, classifier ----------------
__global__ __launch_bounds__(256) void final_kernel(
    const float* __restrict__ cz0, const float* __restrict__ cz1,
    const float* __restrict__ attn1_W, const float* __restrict__ attn1_b,
    const float* __restrict__ attn2_W, const float* __restrict__ attn2_b,
    const float* __restrict__ cls_W, const float* __restrict__ cls_b,
    float* __restrict__ out) {
  int wave = threadIdx.x >> 6, lane = threadIdx.x & 63;
  int n = blockIdx.x * 4 + wave;
  if (n >= NNODES) return;
  size_t idx = (size_t)n * HD + lane;

  float z0 = cz0[idx];
  float z1 = cz1[idx];

  float m0 = wave_bsum(z0) * (1.f / 64.f);
  float dv0 = z0 - m0;
  float var0 = wave_bsum(dv0 * dv0) * (1.f / 64.f);
  float y0 = dv0 * rsqrtf(var0 + 1e-5f);
  float g0 = 0.5f * y0 * (1.f + erff(y0 * 0.70710678118654752f));

  float m1 = wave_bsum(z1) * (1.f / 64.f);
  float dv1 = z1 - m1;
  float var1 = wave_bsum(dv1 * dv1) * (1.f / 64.f);
  float y1 = dv1 * rsqrtf(var1 + 1e-5f);
  float g1 = 0.5f * y1 * (1.f + erff(y1 * 0.70710678118654752f));

  float t0 = attn1_b[lane], t1 = attn1_b[lane];
#pragma unroll 8
  for (int j = 0; j < 64; j++) {
    float w = attn1_W[j * HD + lane];
    t0 = fmaf(__shfl(g0, j, 64), w, t0);
    t1 = fmaf(__shfl(g1, j, 64), w, t1);
  }
  t0 = tanhf(t0);
  t1 = tanhf(t1);
  float aw = attn2_W[lane];
  float a0 = wave_bsum(t0 * aw) + attn2_b[0];
  float a1 = wave_bsum(t1 * aw) + attn2_b[0];
  float mx = fmaxf(a0, a1);
  float e0 = expf(a0 - mx), e1 = expf(a1 - mx);
  float inv = 1.f / (e0 + e1);
  float p0 = e0 * inv, p1 = e1 * inv;
  float o = p0 * g0 + p1 * g1;

#pragma unroll
  for (int k = 0; k < 8; k++) {
    float s = wave_bsum(o * cls_W[lane * 8 + k]);
    if (lane == k) out[(size_t)n * 8 + k] = s + cls_b[k];
  }
}

extern "C" void kernel_launch(void* const* d_in, const int* in_sizes, int n_in,
                              void* d_out, int out_size, void* d_ws, size_t ws_size,
                              hipStream_t stream) {
  const float* node_feats   = (const float*)d_in[0];
  const int*   node_types   = (const int*)d_in[1];
  const int*   adj_rows     = (const int*)d_in[2];
  const int*   adj_cols     = (const int*)d_in[3];
  const float* adj_vals     = (const float*)d_in[4];
  const float* type_W       = (const float*)d_in[5];
  const float* type_b       = (const float*)d_in[6];
  const float* aW0          = (const float*)d_in[7];
  const float* ab0          = (const float*)d_in[8];
  const float* aW1          = (const float*)d_in[9];
  const float* ab1          = (const float*)d_in[10];
  const float* as_seq0      = (const float*)d_in[11];
  const float* as_last_seq0 = (const float*)d_in[12];
  const float* as_res0      = (const float*)d_in[13];
  const float* as_last_res0 = (const float*)d_in[14];
  const float* as_seq1      = (const float*)d_in[15];
  const float* as_last_seq1 = (const float*)d_in[16];
  const float* as_last_res1 = (const float*)d_in[17];
  const float* attn1_W      = (const float*)d_in[18];
  const float* attn1_b      = (const float*)d_in[19];
  const float* attn2_W      = (const float*)d_in[20];
  const float* attn2_b      = (const float*)d_in[21];
  const float* cls_W        = (const float*)d_in[22];
  const float* cls_b        = (const float*)d_in[23];
  float* out = (float*)d_out;
  float* ws = (float*)d_ws;

  unsigned int* xpb = (unsigned int*)(ws + XPB_OFF);
  unsigned int* spb = (unsigned int*)(ws + SPB_OFF);
  float* cres = ws + CRES_OFF;
  float* cz0  = ws + CZ0_OFF;
  float* cz1  = ws + CZ1_OFF;
  int2*  epk  = (int2*)(ws + EPK_OFF);
  int*   perm = (int*)(ws + PERM_OFF);
  int*   cnt2 = (int*)(ws + CNT2_OFF);
  int*   off2 = (int*)(ws + OFF2_OFF);
  int*   part = (int*)(ws + PART_OFF);
  int*   off  = (int*)(ws + OFF_OFF);
  int*   cntk = (int*)(ws + CNTK_OFF);
  int*   roff = (int*)(ws + ROFF_OFF);
  float* wc   = ws + WC_OFF;

  wcoef_kernel<<<1, 64, 0, stream>>>(as_seq0, as_last_seq0, as_res0, as_last_res0,
                                     as_seq1, as_last_seq1, as_last_res1, wc);

  hid_kernel<<<NNODES / 4, 256, 0, stream>>>(node_feats, node_types, type_W, type_b,
                                             aW0, ab0, aW1, ab1, xpb);

  // deterministic edge build: hist2 -> scan -> keyoff -> LDS-cursor scatter -> pack+sort
  histb2_kernel<<<dim3(CHK, 4), 256, 0, stream>>>(adj_rows, cnt2);
  scan1_kernel<<<SCAN1B, 256, 0, stream>>>(cnt2, off2, part);
  scan2_kernel<<<1, 1024, 0, stream>>>(part);
  scan3_kernel<<<SCAN1B, 256, 0, stream>>>(off2, part);
  keyoff_kernel<<<(NKEY + 255) / 256, 256, 0, stream>>>(off2, off, cntk);
  scatterd_kernel<<<dim3(CHK, 4), 256, 0, stream>>>(adj_rows, off2, perm);
  pack_kernel<<<NKEY, 256, 0, stream>>>(adj_rows, adj_cols, adj_vals, perm, off, cntk,
                                        epk, roff);

  // SpMM stages: pre-sorted edges, register accumulation
  st1_kernel<<<NB, 256, 0, stream>>>(off, cntk, roff, epk, xpb, wc, spb, cres, cz0, cz1);
  st2_kernel<<<NB, 256, 0, stream>>>(off, cntk, roff, epk, spb, wc, cres, cz0, cz1);
  st3_kernel<<<NB, 256, 0, stream>>>(off, cntk, roff, epk, cres, wc, cz0);

  final_kernel<<<NNODES / 4, 256, 0, stream>>>(cz0, cz1,
                                               attn1_W, attn1_b, attn2_W, attn2_b,
                                               cls_W, cls_b, out);
}

// Round 8
// 1847.470 us; speedup vs baseline: 1.3373x; 1.1024x over previous
//
#include <hip/hip_runtime.h>
#include <math.h>

// Problem constants (match reference file)
#define NNODES 100000
#define NEDGE  1600000
#define HD     64
#define INDIM  256

#define RB   32                 // rows per bucket
#define NB   3125               // NNODES / RB (exact)
#define NKEY (4 * NB)           // 12500 (a, bucket) regions
#define CAP  1024               // edges per LDS chunk (Poisson(512) -> never exceeded)
#define CHK  64                 // chunks per adjacency (deterministic scatter)
#define EPC  (NEDGE / CHK)      // 25000 edges per chunk
#define NCH  100                // node chunks (type sort)
#define NPC  (NNODES / NCH)     // 1000 nodes per chunk

static constexpr size_t NP = (size_t)NNODES * HD;   // 6.4M floats per [N,H] plane
static constexpr size_t ME = (size_t)4 * NEDGE;     // 6.4M edges total
static constexpr int    M2 = NKEY * CHK;            // 800000 (key,chunk) counters
static constexpr int    SCAN1B = (M2 + 1023) / 1024;  // 782

// workspace layout (floats) — total ~200.5 MB (< 212 MB proven available in R7)
static constexpr size_t XPB_OFF   = 0;                   // uint bf16x2 (x0,x1): NP
static constexpr size_t SPB_OFF   = NP;                  // uint bf16x2 (s1,t1): NP
static constexpr size_t CRES_OFF  = 2 * NP;              // s2 accumulator (f32)
static constexpr size_t CZ0_OFF   = 3 * NP;              // z0 (f32)
static constexpr size_t CZ1_OFF   = 4 * NP;              // z1 (f32)
static constexpr size_t S2B_OFF   = 5 * NP;              // ushort bf16 s2: NP/2 floats
static constexpr size_t EPK_OFF   = 5 * NP + NP / 2;     // int2 (lr|col,val): 2*ME
static constexpr size_t CNT2_OFF  = EPK_OFF + 2 * ME;    // M2 ints [key][chunk]
static constexpr size_t OFF2_OFF  = CNT2_OFF + M2;       // M2 ints
static constexpr size_t PART_OFF  = OFF2_OFF + M2;       // 1024 ints
static constexpr size_t OFF_OFF   = PART_OFF + 1024;     // NKEY ints
static constexpr size_t CNTK_OFF  = OFF_OFF + NKEY;      // NKEY ints
static constexpr size_t ROFF_OFF  = CNTK_OFF + NKEY;     // NKEY*RB ints
static constexpr size_t NCNT_OFF  = ROFF_OFF + (size_t)NKEY * RB;  // 512 ints
static constexpr size_t NOFF_OFF  = NCNT_OFF + 512;      // 512 ints
static constexpr size_t NPERM_OFF = NOFF_OFF + 512;      // NNODES ints
static constexpr size_t WC_OFF    = NPERM_OFF + NNODES;  // 26 floats

// ---------------- helpers ----------------
__device__ __forceinline__ float wave_bsum(float v) {
#pragma unroll
  for (int m = 1; m < 64; m <<= 1) v += __shfl_xor(v, m, 64);
  return v;
}

__device__ __forceinline__ unsigned int bf2pack(float a, float b) {
  unsigned int ua = __float_as_uint(a);
  ua += 0x7FFFu + ((ua >> 16) & 1u);        // RNE
  unsigned int ub = __float_as_uint(b);
  ub += 0x7FFFu + ((ub >> 16) & 1u);
  return (ua >> 16) | (ub & 0xFFFF0000u);
}
__device__ __forceinline__ unsigned short bf1(float a) {
  unsigned int ua = __float_as_uint(a);
  ua += 0x7FFFu + ((ua >> 16) & 1u);
  return (unsigned short)(ua >> 16);
}
__device__ __forceinline__ float bf_lo(unsigned int g) { return __uint_as_float(g << 16); }
__device__ __forceinline__ float bf_hi(unsigned int g) { return __uint_as_float(g & 0xFFFF0000u); }

// ---------------- arch-weight softmax coefficients ----------------
// wc layout:
//  [0..2]   softmax(as_seq0 row0)/3      (s1 from S0[0..2])
//  [3..5]   softmax(as_seq0 row1)/3      (s2 seq part from S1[0..2])
//  [6..9]   softmax(as_res0)/4           (s2 res part from S0[0..3])
//  [10..11] softmax(as_last_seq0)/2      (z0 from S2[0..1])
//  [12..14] softmax(as_last_res0 row0)/3 (z0 from S0[0,1,3])
//  [15..17] softmax(as_last_res0 row1)/3 (z0 from S1[0,1,3])
//  [18..20] softmax(as_seq1)/3           (t1 from T0[0..2])
//  [21..22] softmax(as_last_seq1)/2      (z1 from T1[0..1])
//  [23..25] softmax(as_last_res1)/3      (z1 from T0[0,1,3])
__global__ void wcoef_kernel(const float* __restrict__ s0, const float* __restrict__ ls0,
                             const float* __restrict__ r0, const float* __restrict__ lr0,
                             const float* __restrict__ s1, const float* __restrict__ ls1,
                             const float* __restrict__ lr1, float* __restrict__ wc) {
  if (threadIdx.x != 0 || blockIdx.x != 0) return;
  auto sm2 = [](const float* a, float* o, float sc) {
    float m = fmaxf(a[0], a[1]);
    float e0 = expf(a[0] - m), e1 = expf(a[1] - m);
    float inv = sc / (e0 + e1);
    o[0] = e0 * inv; o[1] = e1 * inv;
  };
  auto sm3 = [](const float* a, float* o, float sc) {
    float m = fmaxf(a[0], fmaxf(a[1], a[2]));
    float e0 = expf(a[0] - m), e1 = expf(a[1] - m), e2 = expf(a[2] - m);
    float inv = sc / (e0 + e1 + e2);
    o[0] = e0 * inv; o[1] = e1 * inv; o[2] = e2 * inv;
  };
  auto sm4 = [](const float* a, float* o, float sc) {
    float m = fmaxf(fmaxf(a[0], a[1]), fmaxf(a[2], a[3]));
    float e0 = expf(a[0] - m), e1 = expf(a[1] - m), e2 = expf(a[2] - m), e3 = expf(a[3] - m);
    float inv = sc / (e0 + e1 + e2 + e3);
    o[0] = e0 * inv; o[1] = e1 * inv; o[2] = e2 * inv; o[3] = e3 * inv;
  };
  sm3(s0,      wc + 0,  1.f / 3.f);
  sm3(s0 + 3,  wc + 3,  1.f / 3.f);
  sm4(r0,      wc + 6,  0.25f);
  sm2(ls0,     wc + 10, 0.5f);
  sm3(lr0,     wc + 12, 1.f / 3.f);
  sm3(lr0 + 3, wc + 15, 1.f / 3.f);
  sm3(s1,      wc + 18, 1.f / 3.f);
  sm2(ls1,     wc + 21, 0.5f);
  sm3(lr1,     wc + 23, 1.f / 3.f);
}

// ================= node type sort (deterministic, chunked) =================
__global__ __launch_bounds__(256) void nhist_kernel(const int* __restrict__ types,
                                                    int* __restrict__ ncnt) {
  __shared__ int c[4];
  int ch = blockIdx.x;
  if (threadIdx.x < 4) c[threadIdx.x] = 0;
  __syncthreads();
  int base = ch * NPC;
  for (int i = base + threadIdx.x; i < base + NPC; i += 256)
    atomicAdd(&c[types[i]], 1);
  __syncthreads();
  if (threadIdx.x < 4) ncnt[threadIdx.x * NCH + ch] = c[threadIdx.x];
}

__global__ __launch_bounds__(256) void nscan_kernel(const int* __restrict__ ncnt,
                                                    int* __restrict__ noff) {
  __shared__ int sdata[256];
  int t = threadIdx.x;
  int i0 = t * 2;
  int v0 = (i0 < 4 * NCH) ? ncnt[i0] : 0;
  int v1 = (i0 + 1 < 4 * NCH) ? ncnt[i0 + 1] : 0;
  int ts = v0 + v1;
  sdata[t] = ts;
  __syncthreads();
  for (int o = 1; o < 256; o <<= 1) {
    int x = (t >= o) ? sdata[t - o] : 0;
    __syncthreads();
    sdata[t] += x;
    __syncthreads();
  }
  int excl = sdata[t] - ts;
  if (i0 < 4 * NCH) noff[i0] = excl;
  if (i0 + 1 < 4 * NCH) noff[i0 + 1] = excl + v0;
}

__global__ __launch_bounds__(256) void nscatter_kernel(const int* __restrict__ types,
                                                       const int* __restrict__ noff,
                                                       int* __restrict__ nperm) {
  __shared__ int cur[4];
  int ch = blockIdx.x;
  if (threadIdx.x < 4) cur[threadIdx.x] = noff[threadIdx.x * NCH + ch];
  __syncthreads();
  int base = ch * NPC;
  for (int i = base + threadIdx.x; i < base + NPC; i += 256) {
    int pos = atomicAdd(&cur[types[i]], 1);
    nperm[pos] = i;
  }
}

// ---------------- typed projection + both affines, type-sorted, 8 nodes/wave ----------------
__global__ __launch_bounds__(256) void hid2_kernel(
    const float* __restrict__ feats, const int* __restrict__ types,
    const int* __restrict__ nperm,
    const float* __restrict__ type_W, const float* __restrict__ type_b,
    const float* __restrict__ W0, const float* __restrict__ b0,
    const float* __restrict__ W1, const float* __restrict__ b1,
    unsigned int* __restrict__ xpb) {
  __shared__ float sh_h[4][8][64];
  int t = threadIdx.x, wv = t >> 6, lane = t & 63;
  int idx0 = blockIdx.x * 32 + wv * 8;
  int nj[8];
#pragma unroll
  for (int j = 0; j < 8; j++)
    nj[j] = __builtin_amdgcn_readfirstlane(nperm[idx0 + j]);
  int t0 = __builtin_amdgcn_readfirstlane(types[nj[0]]);
  int t7 = __builtin_amdgcn_readfirstlane(types[nj[7]]);
  float acc[8];
  if (t0 == t7) {
    // uniform type: W loads shared across 8 nodes
    const float* W = type_W + (size_t)t0 * (INDIM * HD);
    float bias = type_b[t0 * HD + lane];
#pragma unroll
    for (int j = 0; j < 8; j++) acc[j] = bias;
    for (int k = 0; k < INDIM; k += 4) {
#pragma unroll
      for (int kk = 0; kk < 4; kk++) {
        float wk = W[(k + kk) * HD + lane];
#pragma unroll
        for (int j = 0; j < 8; j++)
          acc[j] = fmaf(feats[(size_t)nj[j] * INDIM + k + kk], wk, acc[j]);
      }
    }
  } else {
    // boundary wave (rare): per-node
    for (int j = 0; j < 8; j++) {
      int tj = __builtin_amdgcn_readfirstlane(types[nj[j]]);
      const float* W = type_W + (size_t)tj * (INDIM * HD);
      float a = type_b[tj * HD + lane];
      for (int k = 0; k < INDIM; k++)
        a = fmaf(feats[(size_t)nj[j] * INDIM + k], W[k * HD + lane], a);
      acc[j] = a;
    }
  }
#pragma unroll
  for (int j = 0; j < 8; j++) sh_h[wv][j][lane] = acc[j];
  // wave-private LDS region: no __syncthreads needed
  float a0[8], a1[8];
  float bb0 = b0[lane], bb1 = b1[lane];
#pragma unroll
  for (int j = 0; j < 8; j++) { a0[j] = bb0; a1[j] = bb1; }
  for (int j2 = 0; j2 < 64; j2++) {
    float w0 = W0[j2 * HD + lane], w1 = W1[j2 * HD + lane];
#pragma unroll
    for (int j = 0; j < 8; j++) {
      float hv = sh_h[wv][j][j2];
      a0[j] = fmaf(hv, w0, a0[j]);
      a1[j] = fmaf(hv, w1, a1[j]);
    }
  }
#pragma unroll
  for (int j = 0; j < 8; j++)
    xpb[(size_t)nj[j] * HD + lane] = bf2pack(a0[j], a1[j]);
}

// ================= deterministic two-pass edge build (no global atomics) =================
__global__ __launch_bounds__(256) void histb2_kernel(const int* __restrict__ rows,
                                                     int* __restrict__ cnt2) {
  __shared__ int h[NB];
  int a = blockIdx.y, ch = blockIdx.x;
  for (int i = threadIdx.x; i < NB; i += 256) h[i] = 0;
  __syncthreads();
  int base = ch * EPC;
  for (int e = base + threadIdx.x; e < base + EPC; e += 256)
    atomicAdd(&h[rows[(size_t)a * NEDGE + e] >> 5], 1);
  __syncthreads();
  for (int b = threadIdx.x; b < NB; b += 256)
    cnt2[((size_t)(a * NB + b) << 6) | ch] = h[b];
}

__global__ __launch_bounds__(256) void scan1_kernel(const int* __restrict__ cnt2,
                                                    int* __restrict__ off2,
                                                    int* __restrict__ part) {
  __shared__ int sdata[256];
  int t = threadIdx.x;
  int base = blockIdx.x * 1024 + t * 4;
  int v0 = (base + 0 < M2) ? cnt2[base + 0] : 0;
  int v1 = (base + 1 < M2) ? cnt2[base + 1] : 0;
  int v2 = (base + 2 < M2) ? cnt2[base + 2] : 0;
  int v3 = (base + 3 < M2) ? cnt2[base + 3] : 0;
  int tsum = v0 + v1 + v2 + v3;
  sdata[t] = tsum;
  __syncthreads();
  for (int o = 1; o < 256; o <<= 1) {
    int x = (t >= o) ? sdata[t - o] : 0;
    __syncthreads();
    sdata[t] += x;
    __syncthreads();
  }
  int excl = sdata[t] - tsum;
  if (t == 255) part[blockIdx.x] = sdata[255];
  if (base + 0 < M2) off2[base + 0] = excl;
  if (base + 1 < M2) off2[base + 1] = excl + v0;
  if (base + 2 < M2) off2[base + 2] = excl + v0 + v1;
  if (base + 3 < M2) off2[base + 3] = excl + v0 + v1 + v2;
}

__global__ __launch_bounds__(1024) void scan2_kernel(int* __restrict__ part) {
  __shared__ int sdata[1024];
  int t = threadIdx.x;
  int v = (t < SCAN1B) ? part[t] : 0;
  sdata[t] = v;
  __syncthreads();
  for (int o = 1; o < 1024; o <<= 1) {
    int x = (t >= o) ? sdata[t - o] : 0;
    __syncthreads();
    sdata[t] += x;
    __syncthreads();
  }
  if (t < SCAN1B) part[t] = sdata[t] - v;  // exclusive
}

__global__ __launch_bounds__(256) void scan3_kernel(int* __restrict__ off2,
                                                    const int* __restrict__ part) {
  int p = part[blockIdx.x];
  int t = threadIdx.x;
#pragma unroll
  for (int j = 0; j < 4; j++) {
    int i = blockIdx.x * 1024 + j * 256 + t;
    if (i < M2) off2[i] += p;
  }
}

__global__ __launch_bounds__(256) void keyoff_kernel(const int* __restrict__ off2,
                                                     int* __restrict__ off,
                                                     int* __restrict__ cntk) {
  int k = blockIdx.x * 256 + threadIdx.x;
  if (k >= NKEY) return;
  int s = off2[(size_t)k << 6];
  int e = (k + 1 < NKEY) ? off2[(size_t)(k + 1) << 6] : (int)ME;
  off[k] = s;
  cntk[k] = e - s;
}

// pass 2: deterministic scatter of packed (lr|col,val) using LDS cursors
__global__ __launch_bounds__(256) void scatterd_kernel(
    const int* __restrict__ rows, const int* __restrict__ cols, const float* __restrict__ vals,
    const int* __restrict__ off2, int2* __restrict__ epk) {
  __shared__ int cur[NB];
  int a = blockIdx.y, ch = blockIdx.x;
  for (int b = threadIdx.x; b < NB; b += 256)
    cur[b] = off2[((size_t)(a * NB + b) << 6) | ch];
  __syncthreads();
  int base = ch * EPC;
  for (int e = base + threadIdx.x; e < base + EPC; e += 256) {
    size_t idx = (size_t)a * NEDGE + e;
    int r = rows[idx];
    int pos = atomicAdd(&cur[r >> 5], 1);
    epk[pos] = make_int2(((r & 31) << 17) | cols[idx], __float_as_int(vals[idx]));
  }
}

// pack: per bucket, coalesced read epk region, counting-sort by local row in LDS,
// write back sorted + rofftab
__global__ __launch_bounds__(256) void pack_kernel(
    const int* __restrict__ off, const int* __restrict__ cnt,
    int2* __restrict__ epk, int* __restrict__ rofftab) {
  __shared__ int smeta[CAP];
  __shared__ float sval[CAP];
  __shared__ int h[RB], hc[RB];
  int key = blockIdx.x;
  int base = off[key], n = cnt[key];
  int t = threadIdx.x, wv = t >> 6, lane = t & 63;
  if (t < RB) h[t] = 0;
  __syncthreads();
  if (n <= CAP) {
    int lm[4]; float lv[4];
    int cl = 0;
#pragma unroll
    for (int j = 0; j < 4; j++) {
      int i = t + j * 256;
      if (i < n) {
        int2 p = epk[base + i];
        lm[cl] = p.x;
        lv[cl] = __int_as_float(p.y);
        cl++;
        atomicAdd(&h[p.x >> 17], 1);
      }
    }
    __syncthreads();
    if (wv == 0) {
      int v = (lane < RB) ? h[lane] : 0;
      int incl = v;
#pragma unroll
      for (int o = 1; o < RB; o <<= 1) {
        int x = __shfl_up(incl, o, 64);
        if (lane >= o) incl += x;
      }
      if (lane < RB) {
        int excl = incl - v;
        hc[lane] = excl;
        rofftab[(size_t)key * RB + lane] = excl;
      }
    }
    __syncthreads();
    for (int j = 0; j < cl; j++) {
      int p = atomicAdd(&hc[lm[j] >> 17], 1);
      smeta[p] = lm[j];
      sval[p] = lv[j];
    }
    __syncthreads();
    for (int i = t; i < n; i += 256)
      epk[base + i] = make_int2(smeta[i], __float_as_int(sval[i]));
  }
  // n > CAP: leave unsorted; stages use slow scan path (never expected)
}

// ================= SpMM stages: sorted epk, LDS staging, register accumulation =====

// stage 1: gather xpb (bf16 x0,x1); write spb(bf16 s1,t1), cres, cz0, cz1
__global__ __launch_bounds__(256) void st1_kernel(
    const int* __restrict__ off, const int* __restrict__ cnt,
    const int* __restrict__ rofftab, const int2* __restrict__ epk,
    const unsigned int* __restrict__ xpb, const float* __restrict__ wc,
    unsigned int* __restrict__ spb, float* __restrict__ cres,
    float* __restrict__ cz0, float* __restrict__ cz1) {
  __shared__ int scol[CAP];
  __shared__ float sv[CAP];
  __shared__ int ro[RB + 1];
  int b = blockIdx.x, t = threadIdx.x;
  int wv = t >> 6, lane = t & 63;
  float as1[8], at1[8], ares[8], az0[8], az1[8];
#pragma unroll
  for (int r = 0; r < 8; r++) { as1[r] = 0.f; at1[r] = 0.f; ares[r] = 0.f; az0[r] = 0.f; az1[r] = 0.f; }
  for (int a = 0; a < 4; a++) {
    int key = a * NB + b;
    int base = off[key], n = cnt[key];
    float w_s1  = (a < 3) ? wc[a] : 0.f;
    float w_res = wc[6 + a];
    float w_z0  = (a == 3) ? wc[14] : ((a < 2) ? wc[12 + a] : 0.f);
    float w_t1  = (a < 3) ? wc[18 + a] : 0.f;
    float w_z1  = (a == 3) ? wc[25] : ((a < 2) ? wc[23 + a] : 0.f);
    if (n <= CAP) {
      __syncthreads();
      if (t < RB) ro[t] = rofftab[(size_t)key * RB + t];
      if (t == RB) ro[RB] = n;
      for (int i = t; i < n; i += 256) {
        int2 p = epk[base + i];
        scol[i] = p.x & 0x1FFFF;
        sv[i] = __int_as_float(p.y);
      }
      __syncthreads();
#pragma unroll
      for (int r8 = 0; r8 < 8; r8++) {
        int r = wv * 8 + r8;
        int s0 = ro[r], e0 = ro[r + 1];
        float accs = 0.f, acct = 0.f;
        int i = s0;
        for (; i + 1 < e0; i += 2) {
          int c0 = scol[i], c1 = scol[i + 1];
          float v0 = sv[i], v1 = sv[i + 1];
          unsigned int g0 = xpb[(size_t)c0 * 64 + lane];
          unsigned int g1 = xpb[(size_t)c1 * 64 + lane];
          accs = fmaf(v0, bf_lo(g0), accs); acct = fmaf(v0, bf_hi(g0), acct);
          accs = fmaf(v1, bf_lo(g1), accs); acct = fmaf(v1, bf_hi(g1), acct);
        }
        if (i < e0) {
          unsigned int g0 = xpb[(size_t)scol[i] * 64 + lane];
          accs = fmaf(sv[i], bf_lo(g0), accs); acct = fmaf(sv[i], bf_hi(g0), acct);
        }
        as1[r8]  = fmaf(w_s1, accs, as1[r8]);
        ares[r8] = fmaf(w_res, accs, ares[r8]);
        az0[r8]  = fmaf(w_z0, accs, az0[r8]);
        at1[r8]  = fmaf(w_t1, acct, at1[r8]);
        az1[r8]  = fmaf(w_z1, acct, az1[r8]);
      }
    } else {
      // slow scan (unsorted; never expected)
      for (int i = 0; i < n; i++) {
        int2 p = epk[base + i];
        int lr = p.x >> 17, c = p.x & 0x1FFFF;
        float v = __int_as_float(p.y);
        unsigned int g = xpb[(size_t)c * 64 + lane];
        float gs = v * bf_lo(g), gt = v * bf_hi(g);
#pragma unroll
        for (int r8 = 0; r8 < 8; r8++) {
          if (lr == wv * 8 + r8) {
            as1[r8]  = fmaf(w_s1, gs, as1[r8]);
            ares[r8] = fmaf(w_res, gs, ares[r8]);
            az0[r8]  = fmaf(w_z0, gs, az0[r8]);
            at1[r8]  = fmaf(w_t1, gt, at1[r8]);
            az1[r8]  = fmaf(w_z1, gt, az1[r8]);
          }
        }
      }
    }
  }
  int rowbase = b * RB + wv * 8;
#pragma unroll
  for (int r8 = 0; r8 < 8; r8++) {
    size_t o = (size_t)(rowbase + r8) * 64 + lane;
    spb[o] = bf2pack(as1[r8], at1[r8]);
    cres[o] = ares[r8];
    cz0[o] = az0[r8];
    cz1[o] = az1[r8];
  }
}

// stage 2: gather spb (bf16 s1,t1); add into cres (s2 seq)+emit s2b, cz0, cz1
__global__ __launch_bounds__(256) void st2_kernel(
    const int* __restrict__ off, const int* __restrict__ cnt,
    const int* __restrict__ rofftab, const int2* __restrict__ epk,
    const unsigned int* __restrict__ spb, const float* __restrict__ wc,
    float* __restrict__ cres, unsigned short* __restrict__ s2b,
    float* __restrict__ cz0, float* __restrict__ cz1) {
  __shared__ int scol[CAP];
  __shared__ float sv[CAP];
  __shared__ int ro[RB + 1];
  int b = blockIdx.x, t = threadIdx.x;
  int wv = t >> 6, lane = t & 63;
  float dres[8], dz0[8], dz1[8];
#pragma unroll
  for (int r = 0; r < 8; r++) { dres[r] = 0.f; dz0[r] = 0.f; dz1[r] = 0.f; }
  for (int a = 0; a < 4; a++) {
    int key = a * NB + b;
    int base = off[key], n = cnt[key];
    float w_seq = (a < 3) ? wc[3 + a] : 0.f;
    float w_z0  = (a == 3) ? wc[17] : ((a < 2) ? wc[15 + a] : 0.f);
    float w_z1  = (a < 2) ? wc[21 + a] : 0.f;
    if (n <= CAP) {
      __syncthreads();
      if (t < RB) ro[t] = rofftab[(size_t)key * RB + t];
      if (t == RB) ro[RB] = n;
      for (int i = t; i < n; i += 256) {
        int2 p = epk[base + i];
        scol[i] = p.x & 0x1FFFF;
        sv[i] = __int_as_float(p.y);
      }
      __syncthreads();
#pragma unroll
      for (int r8 = 0; r8 < 8; r8++) {
        int r = wv * 8 + r8;
        int s0 = ro[r], e0 = ro[r + 1];
        float accs = 0.f, acct = 0.f;
        int i = s0;
        for (; i + 1 < e0; i += 2) {
          int c0 = scol[i], c1 = scol[i + 1];
          float v0 = sv[i], v1 = sv[i + 1];
          unsigned int g0 = spb[(size_t)c0 * 64 + lane];
          unsigned int g1 = spb[(size_t)c1 * 64 + lane];
          accs = fmaf(v0, bf_lo(g0), accs); acct = fmaf(v0, bf_hi(g0), acct);
          accs = fmaf(v1, bf_lo(g1), accs); acct = fmaf(v1, bf_hi(g1), acct);
        }
        if (i < e0) {
          unsigned int g0 = spb[(size_t)scol[i] * 64 + lane];
          accs = fmaf(sv[i], bf_lo(g0), accs); acct = fmaf(sv[i], bf_hi(g0), acct);
        }
        dres[r8] = fmaf(w_seq, accs, dres[r8]);
        dz0[r8]  = fmaf(w_z0, accs, dz0[r8]);
        dz1[r8]  = fmaf(w_z1, acct, dz1[r8]);
      }
    } else {
      for (int i = 0; i < n; i++) {
        int2 p = epk[base + i];
        int lr = p.x >> 17, c = p.x & 0x1FFFF;
        float v = __int_as_float(p.y);
        unsigned int g = spb[(size_t)c * 64 + lane];
        float gs = v * bf_lo(g), gt = v * bf_hi(g);
#pragma unroll
        for (int r8 = 0; r8 < 8; r8++) {
          if (lr == wv * 8 + r8) {
            dres[r8] = fmaf(w_seq, gs, dres[r8]);
            dz0[r8]  = fmaf(w_z0, gs, dz0[r8]);
            dz1[r8]  = fmaf(w_z1, gt, dz1[r8]);
          }
        }
      }
    }
  }
  int rowbase = b * RB + wv * 8;
#pragma unroll
  for (int r8 = 0; r8 < 8; r8++) {
    size_t o = (size_t)(rowbase + r8) * 64 + lane;
    float s2v = cres[o] + dres[r8];
    cres[o] = s2v;
    s2b[o] = bf1(s2v);
    cz0[o] += dz0[r8];
    cz1[o] += dz1[r8];
  }
}

// stage 3: gather s2b (bf16) on adjs 0,1 (weight folded); add into cz0
__global__ __launch_bounds__(256) void st3_kernel(
    const int* __restrict__ off, const int* __restrict__ cnt,
    const int* __restrict__ rofftab, const int2* __restrict__ epk,
    const unsigned short* __restrict__ s2b, const float* __restrict__ wc,
    float* __restrict__ cz0) {
  __shared__ int scol[CAP];
  __shared__ float sv[CAP];
  __shared__ int ro[RB + 1];
  int b = blockIdx.x, t = threadIdx.x;
  int wv = t >> 6, lane = t & 63;
  float dz[8];
#pragma unroll
  for (int r = 0; r < 8; r++) dz[r] = 0.f;
  for (int a = 0; a < 2; a++) {
    int key = a * NB + b;
    int base = off[key], n = cnt[key];
    float w = wc[10 + a];
    if (n <= CAP) {
      __syncthreads();
      if (t < RB) ro[t] = rofftab[(size_t)key * RB + t];
      if (t == RB) ro[RB] = n;
      for (int i = t; i < n; i += 256) {
        int2 p = epk[base + i];
        scol[i] = p.x & 0x1FFFF;
        sv[i] = __int_as_float(p.y);
      }
      __syncthreads();
#pragma unroll
      for (int r8 = 0; r8 < 8; r8++) {
        int r = wv * 8 + r8;
        int s0 = ro[r], e0 = ro[r + 1];
        float accs = 0.f;
        int i = s0;
        for (; i + 1 < e0; i += 2) {
          float g0 = __uint_as_float((unsigned int)s2b[(size_t)scol[i] * 64 + lane] << 16);
          float g1 = __uint_as_float((unsigned int)s2b[(size_t)scol[i + 1] * 64 + lane] << 16);
          accs = fmaf(sv[i], g0, accs);
          accs = fmaf(sv[i + 1], g1, accs);
        }
        if (i < e0) {
          float g0 = __uint_as_float((unsigned int)s2b[(size_t)scol[i] * 64 + lane] << 16);
          accs = fmaf(sv[i], g0, accs);
        }
        dz[r8] = fmaf(w, accs, dz[r8]);
      }
    } else {
      for (int i = 0; i < n; i++) {
        int2 p = epk[base + i];
        int lr = p.x >> 17, c = p.x & 0x1FFFF;
        float v = __int_as_float(p.y);
        float g = __uint_as_float((unsigned int)s2b[(size_t)c * 64 + lane] << 16);
        float gs = v * g;
#pragma unroll
        for (int r8 = 0; r8 < 8; r8++) {
          if (lr == wv * 8 + r8) dz[r8] = fmaf(w, gs, dz[r8]);
        }
      }
    }
  }
  int rowbase = b * RB + wv * 8;
#pragma unroll
  for (int r8 = 0; r8 < 8; r8++) {
    size_t o = (size_t)(rowbase + r8) * 64 + lane;
    cz0[o] += dz[r8];
  }
}

// ---------------- final: LN+gelu both cells, semantic attention, classifier ----------------
__global__ __launch_bounds__(256) void final_kernel(
    const float* __restrict__ cz0, const float* __restrict__ cz1,
    const float* __restrict__ attn1_W, const float* __restrict__ attn1_b,
    const float* __restrict__ attn2_W, const float* __restrict__ attn2_b,
    const float* __restrict__ cls_W, const float* __restrict__ cls_b,
    float* __restrict__ out) {
  int wave = threadIdx.x >> 6, lane = threadIdx.x & 63;
  int n = blockIdx.x * 4 + wave;
  if (n >= NNODES) return;
  size_t idx = (size_t)n * HD + lane;

  float z0 = cz0[idx];
  float z1 = cz1[idx];

  float m0 = wave_bsum(z0) * (1.f / 64.f);
  float dv0 = z0 - m0;
  float var0 = wave_bsum(dv0 * dv0) * (1.f / 64.f);
  float y0 = dv0 * rsqrtf(var0 + 1e-5f);
  float g0 = 0.5f * y0 * (1.f + erff(y0 * 0.70710678118654752f));

  float m1 = wave_bsum(z1) * (1.f / 64.f);
  float dv1 = z1 - m1;
  float var1 = wave_bsum(dv1 * dv1) * (1.f / 64.f);
  float y1 = dv1 * rsqrtf(var1 + 1e-5f);
  float g1 = 0.5f * y1 * (1.f + erff(y1 * 0.70710678118654752f));

  float t0 = attn1_b[lane], t1 = attn1_b[lane];
#pragma unroll 8
  for (int j = 0; j < 64; j++) {
    float w = attn1_W[j * HD + lane];
    t0 = fmaf(__shfl(g0, j, 64), w, t0);
    t1 = fmaf(__shfl(g1, j, 64), w, t1);
  }
  t0 = tanhf(t0);
  t1 = tanhf(t1);
  float aw = attn2_W[lane];
  float a0 = wave_bsum(t0 * aw) + attn2_b[0];
  float a1 = wave_bsum(t1 * aw) + attn2_b[0];
  float mx = fmaxf(a0, a1);
  float e0 = expf(a0 - mx), e1 = expf(a1 - mx);
  float inv = 1.f / (e0 + e1);
  float p0 = e0 * inv, p1 = e1 * inv;
  float o = p0 * g0 + p1 * g1;

#pragma unroll
  for (int k = 0; k < 8; k++) {
    float s = wave_bsum(o * cls_W[lane * 8 + k]);
    if (lane == k) out[(size_t)n * 8 + k] = s + cls_b[k];
  }
}

extern "C" void kernel_launch(void* const* d_in, const int* in_sizes, int n_in,
                              void* d_out, int out_size, void* d_ws, size_t ws_size,
                              hipStream_t stream) {
  const float* node_feats   = (const float*)d_in[0];
  const int*   node_types   = (const int*)d_in[1];
  const int*   adj_rows     = (const int*)d_in[2];
  const int*   adj_cols     = (const int*)d_in[3];
  const float* adj_vals     = (const float*)d_in[4];
  const float* type_W       = (const float*)d_in[5];
  const float* type_b       = (const float*)d_in[6];
  const float* aW0          = (const float*)d_in[7];
  const float* ab0          = (const float*)d_in[8];
  const float* aW1          = (const float*)d_in[9];
  const float* ab1          = (const float*)d_in[10];
  const float* as_seq0      = (const float*)d_in[11];
  const float* as_last_seq0 = (const float*)d_in[12];
  const float* as_res0      = (const float*)d_in[13];
  const float* as_last_res0 = (const float*)d_in[14];
  const float* as_seq1      = (const float*)d_in[15];
  const float* as_last_seq1 = (const float*)d_in[16];
  const float* as_last_res1 = (const float*)d_in[17];
  const float* attn1_W      = (const float*)d_in[18];
  const float* attn1_b      = (const float*)d_in[19];
  const float* attn2_W      = (const float*)d_in[20];
  const float* attn2_b      = (const float*)d_in[21];
  const float* cls_W        = (const float*)d_in[22];
  const float* cls_b        = (const float*)d_in[23];
  float* out = (float*)d_out;
  float* ws = (float*)d_ws;

  unsigned int*  xpb  = (unsigned int*)(ws + XPB_OFF);
  unsigned int*  spb  = (unsigned int*)(ws + SPB_OFF);
  float*         cres = ws + CRES_OFF;
  float*         cz0  = ws + CZ0_OFF;
  float*         cz1  = ws + CZ1_OFF;
  unsigned short* s2b = (unsigned short*)(ws + S2B_OFF);
  int2*          epk  = (int2*)(ws + EPK_OFF);
  int*           cnt2 = (int*)(ws + CNT2_OFF);
  int*           off2 = (int*)(ws + OFF2_OFF);
  int*           part = (int*)(ws + PART_OFF);
  int*           off  = (int*)(ws + OFF_OFF);
  int*           cntk = (int*)(ws + CNTK_OFF);
  int*           roff = (int*)(ws + ROFF_OFF);
  int*           ncnt = (int*)(ws + NCNT_OFF);
  int*           noff = (int*)(ws + NOFF_OFF);
  int*           nperm = (int*)(ws + NPERM_OFF);
  float*         wc   = ws + WC_OFF;

  wcoef_kernel<<<1, 64, 0, stream>>>(as_seq0, as_last_seq0, as_res0, as_last_res0,
                                     as_seq1, as_last_seq1, as_last_res1, wc);

  // node type sort + typed projection (8 same-type nodes per wave)
  nhist_kernel<<<NCH, 256, 0, stream>>>(node_types, ncnt);
  nscan_kernel<<<1, 256, 0, stream>>>(ncnt, noff);
  nscatter_kernel<<<NCH, 256, 0, stream>>>(node_types, noff, nperm);
  hid2_kernel<<<NNODES / 32, 256, 0, stream>>>(node_feats, node_types, nperm,
                                               type_W, type_b, aW0, ab0, aW1, ab1, xpb);

  // deterministic edge build: hist2 -> scan -> keyoff -> LDS-cursor scatter -> pack+sort
  histb2_kernel<<<dim3(CHK, 4), 256, 0, stream>>>(adj_rows, cnt2);
  scan1_kernel<<<SCAN1B, 256, 0, stream>>>(cnt2, off2, part);
  scan2_kernel<<<1, 1024, 0, stream>>>(part);
  scan3_kernel<<<SCAN1B, 256, 0, stream>>>(off2, part);
  keyoff_kernel<<<(NKEY + 255) / 256, 256, 0, stream>>>(off2, off, cntk);
  scatterd_kernel<<<dim3(CHK, 4), 256, 0, stream>>>(adj_rows, adj_cols, adj_vals, off2, epk);
  pack_kernel<<<NKEY, 256, 0, stream>>>(off, cntk, epk, roff);

  // SpMM stages: pre-sorted edges, register accumulation
  st1_kernel<<<NB, 256, 0, stream>>>(off, cntk, roff, epk, xpb, wc, spb, cres, cz0, cz1);
  st2_kernel<<<NB, 256, 0, stream>>>(off, cntk, roff, epk, spb, wc, cres, s2b, cz0, cz1);
  st3_kernel<<<NB, 256, 0, stream>>>(off, cntk, roff, epk, s2b, wc, cz0);

  final_kernel<<<NNODES / 4, 256, 0, stream>>>(cz0, cz1,
                                               attn1_W, attn1_b, attn2_W, attn2_b,
                                               cls_W, cls_b, out);
}

// Round 9
// 1757.619 us; speedup vs baseline: 1.4057x; 1.0511x over previous
//
#include <hip/hip_runtime.h>
#include <math.h>

// Problem constants (match reference file)
#define NNODES 100000
#define NEDGE  1600000
#define HD     64
#define INDIM  256

#define RB   32                 // rows per bucket
#define NB   3125               // NNODES / RB (exact)
#define NKEY (4 * NB)           // 12500 (a, bucket) regions
#define CAP  1024               // pack LDS capacity
#define CAP2 640                // per-adjacency stage slot (mean 512, +5.7 sigma)
#define CHK  64                 // chunks per adjacency (deterministic scatter)
#define EPC  (NEDGE / CHK)      // 25000 edges per chunk
#define NCH  100                // node chunks (type sort)
#define NPC  (NNODES / NCH)     // 1000 nodes per chunk

static constexpr size_t NP = (size_t)NNODES * HD;   // 6.4M floats per [N,H] plane
static constexpr size_t ME = (size_t)4 * NEDGE;     // 6.4M edges total
static constexpr int    M2 = NKEY * CHK;            // 800000 (key,chunk) counters
static constexpr int    SCAN1B = (M2 + 1023) / 1024;  // 782

// workspace layout (floats) — total ~200.5 MB (< 212 MB proven available in R7)
static constexpr size_t XPB_OFF   = 0;                   // uint bf16x2 (x0,x1): NP
static constexpr size_t SPB_OFF   = NP;                  // uint bf16x2 (s1,t1): NP
static constexpr size_t CRES_OFF  = 2 * NP;              // s2 accumulator (f32)
static constexpr size_t CZ0_OFF   = 3 * NP;              // z0 (f32)
static constexpr size_t CZ1_OFF   = 4 * NP;              // z1 (f32)
static constexpr size_t S2B_OFF   = 5 * NP;              // ushort bf16 s2: NP/2 floats
static constexpr size_t EPK_OFF   = 5 * NP + NP / 2;     // int2 (lr|col,val): 2*ME
static constexpr size_t CNT2_OFF  = EPK_OFF + 2 * ME;    // M2 ints [key][chunk]
static constexpr size_t OFF2_OFF  = CNT2_OFF + M2;       // M2 ints
static constexpr size_t PART_OFF  = OFF2_OFF + M2;       // 1024 ints
static constexpr size_t OFF_OFF   = PART_OFF + 1024;     // NKEY ints
static constexpr size_t CNTK_OFF  = OFF_OFF + NKEY;      // NKEY ints
static constexpr size_t ROFF_OFF  = CNTK_OFF + NKEY;     // NKEY*RB ints
static constexpr size_t NCNT_OFF  = ROFF_OFF + (size_t)NKEY * RB;  // 512 ints
static constexpr size_t NOFF_OFF  = NCNT_OFF + 512;      // 512 ints
static constexpr size_t NPERM_OFF = NOFF_OFF + 512;      // NNODES ints
static constexpr size_t WC_OFF    = NPERM_OFF + NNODES;  // 26 floats

// ---------------- helpers ----------------
__device__ __forceinline__ float wave_bsum(float v) {
#pragma unroll
  for (int m = 1; m < 64; m <<= 1) v += __shfl_xor(v, m, 64);
  return v;
}

__device__ __forceinline__ unsigned int bf2pack(float a, float b) {
  unsigned int ua = __float_as_uint(a);
  ua += 0x7FFFu + ((ua >> 16) & 1u);        // RNE
  unsigned int ub = __float_as_uint(b);
  ub += 0x7FFFu + ((ub >> 16) & 1u);
  return (ua >> 16) | (ub & 0xFFFF0000u);
}
__device__ __forceinline__ unsigned short bf1(float a) {
  unsigned int ua = __float_as_uint(a);
  ua += 0x7FFFu + ((ua >> 16) & 1u);
  return (unsigned short)(ua >> 16);
}
__device__ __forceinline__ float bf_lo(unsigned int g) { return __uint_as_float(g << 16); }
__device__ __forceinline__ float bf_hi(unsigned int g) { return __uint_as_float(g & 0xFFFF0000u); }
__device__ __forceinline__ float bf_s(unsigned short g) {
  return __uint_as_float((unsigned int)g << 16);
}

// ---------------- arch-weight softmax coefficients ----------------
// wc layout:
//  [0..2]   softmax(as_seq0 row0)/3      (s1 from S0[0..2])
//  [3..5]   softmax(as_seq0 row1)/3      (s2 seq part from S1[0..2])
//  [6..9]   softmax(as_res0)/4           (s2 res part from S0[0..3])
//  [10..11] softmax(as_last_seq0)/2      (z0 from S2[0..1])
//  [12..14] softmax(as_last_res0 row0)/3 (z0 from S0[0,1,3])
//  [15..17] softmax(as_last_res0 row1)/3 (z0 from S1[0,1,3])
//  [18..20] softmax(as_seq1)/3           (t1 from T0[0..2])
//  [21..22] softmax(as_last_seq1)/2      (z1 from T1[0..1])
//  [23..25] softmax(as_last_res1)/3      (z1 from T0[0,1,3])
__global__ void wcoef_kernel(const float* __restrict__ s0, const float* __restrict__ ls0,
                             const float* __restrict__ r0, const float* __restrict__ lr0,
                             const float* __restrict__ s1, const float* __restrict__ ls1,
                             const float* __restrict__ lr1, float* __restrict__ wc) {
  if (threadIdx.x != 0 || blockIdx.x != 0) return;
  auto sm2 = [](const float* a, float* o, float sc) {
    float m = fmaxf(a[0], a[1]);
    float e0 = expf(a[0] - m), e1 = expf(a[1] - m);
    float inv = sc / (e0 + e1);
    o[0] = e0 * inv; o[1] = e1 * inv;
  };
  auto sm3 = [](const float* a, float* o, float sc) {
    float m = fmaxf(a[0], fmaxf(a[1], a[2]));
    float e0 = expf(a[0] - m), e1 = expf(a[1] - m), e2 = expf(a[2] - m);
    float inv = sc / (e0 + e1 + e2);
    o[0] = e0 * inv; o[1] = e1 * inv; o[2] = e2 * inv;
  };
  auto sm4 = [](const float* a, float* o, float sc) {
    float m = fmaxf(fmaxf(a[0], a[1]), fmaxf(a[2], a[3]));
    float e0 = expf(a[0] - m), e1 = expf(a[1] - m), e2 = expf(a[2] - m), e3 = expf(a[3] - m);
    float inv = sc / (e0 + e1 + e2 + e3);
    o[0] = e0 * inv; o[1] = e1 * inv; o[2] = e2 * inv; o[3] = e3 * inv;
  };
  sm3(s0,      wc + 0,  1.f / 3.f);
  sm3(s0 + 3,  wc + 3,  1.f / 3.f);
  sm4(r0,      wc + 6,  0.25f);
  sm2(ls0,     wc + 10, 0.5f);
  sm3(lr0,     wc + 12, 1.f / 3.f);
  sm3(lr0 + 3, wc + 15, 1.f / 3.f);
  sm3(s1,      wc + 18, 1.f / 3.f);
  sm2(ls1,     wc + 21, 0.5f);
  sm3(lr1,     wc + 23, 1.f / 3.f);
}

// ================= node type sort (deterministic, chunked) =================
__global__ __launch_bounds__(256) void nhist_kernel(const int* __restrict__ types,
                                                    int* __restrict__ ncnt) {
  __shared__ int c[4];
  int ch = blockIdx.x;
  if (threadIdx.x < 4) c[threadIdx.x] = 0;
  __syncthreads();
  int base = ch * NPC;
  for (int i = base + threadIdx.x; i < base + NPC; i += 256)
    atomicAdd(&c[types[i]], 1);
  __syncthreads();
  if (threadIdx.x < 4) ncnt[threadIdx.x * NCH + ch] = c[threadIdx.x];
}

__global__ __launch_bounds__(256) void nscan_kernel(const int* __restrict__ ncnt,
                                                    int* __restrict__ noff) {
  __shared__ int sdata[256];
  int t = threadIdx.x;
  int i0 = t * 2;
  int v0 = (i0 < 4 * NCH) ? ncnt[i0] : 0;
  int v1 = (i0 + 1 < 4 * NCH) ? ncnt[i0 + 1] : 0;
  int ts = v0 + v1;
  sdata[t] = ts;
  __syncthreads();
  for (int o = 1; o < 256; o <<= 1) {
    int x = (t >= o) ? sdata[t - o] : 0;
    __syncthreads();
    sdata[t] += x;
    __syncthreads();
  }
  int excl = sdata[t] - ts;
  if (i0 < 4 * NCH) noff[i0] = excl;
  if (i0 + 1 < 4 * NCH) noff[i0 + 1] = excl + v0;
}

__global__ __launch_bounds__(256) void nscatter_kernel(const int* __restrict__ types,
                                                       const int* __restrict__ noff,
                                                       int* __restrict__ nperm) {
  __shared__ int cur[4];
  int ch = blockIdx.x;
  if (threadIdx.x < 4) cur[threadIdx.x] = noff[threadIdx.x * NCH + ch];
  __syncthreads();
  int base = ch * NPC;
  for (int i = base + threadIdx.x; i < base + NPC; i += 256) {
    int pos = atomicAdd(&cur[types[i]], 1);
    nperm[pos] = i;
  }
}

// ---------------- typed projection + both affines, type-sorted, 8 nodes/wave ----------------
__global__ __launch_bounds__(256) void hid2_kernel(
    const float* __restrict__ feats, const int* __restrict__ types,
    const int* __restrict__ nperm,
    const float* __restrict__ type_W, const float* __restrict__ type_b,
    const float* __restrict__ W0, const float* __restrict__ b0,
    const float* __restrict__ W1, const float* __restrict__ b1,
    unsigned int* __restrict__ xpb) {
  __shared__ float sh_h[4][8][64];
  int t = threadIdx.x, wv = t >> 6, lane = t & 63;
  int idx0 = blockIdx.x * 32 + wv * 8;
  int nj[8];
#pragma unroll
  for (int j = 0; j < 8; j++)
    nj[j] = __builtin_amdgcn_readfirstlane(nperm[idx0 + j]);
  int t0 = __builtin_amdgcn_readfirstlane(types[nj[0]]);
  int t7 = __builtin_amdgcn_readfirstlane(types[nj[7]]);
  float acc[8];
  if (t0 == t7) {
    const float* W = type_W + (size_t)t0 * (INDIM * HD);
    float bias = type_b[t0 * HD + lane];
#pragma unroll
    for (int j = 0; j < 8; j++) acc[j] = bias;
    for (int k = 0; k < INDIM; k += 4) {
#pragma unroll
      for (int kk = 0; kk < 4; kk++) {
        float wk = W[(k + kk) * HD + lane];
#pragma unroll
        for (int j = 0; j < 8; j++)
          acc[j] = fmaf(feats[(size_t)nj[j] * INDIM + k + kk], wk, acc[j]);
      }
    }
  } else {
    for (int j = 0; j < 8; j++) {
      int tj = __builtin_amdgcn_readfirstlane(types[nj[j]]);
      const float* W = type_W + (size_t)tj * (INDIM * HD);
      float a = type_b[tj * HD + lane];
      for (int k = 0; k < INDIM; k++)
        a = fmaf(feats[(size_t)nj[j] * INDIM + k], W[k * HD + lane], a);
      acc[j] = a;
    }
  }
#pragma unroll
  for (int j = 0; j < 8; j++) sh_h[wv][j][lane] = acc[j];
  float a0[8], a1[8];
  float bb0 = b0[lane], bb1 = b1[lane];
#pragma unroll
  for (int j = 0; j < 8; j++) { a0[j] = bb0; a1[j] = bb1; }
  for (int j2 = 0; j2 < 64; j2++) {
    float w0 = W0[j2 * HD + lane], w1 = W1[j2 * HD + lane];
#pragma unroll
    for (int j = 0; j < 8; j++) {
      float hv = sh_h[wv][j][j2];
      a0[j] = fmaf(hv, w0, a0[j]);
      a1[j] = fmaf(hv, w1, a1[j]);
    }
  }
#pragma unroll
  for (int j = 0; j < 8; j++)
    xpb[(size_t)nj[j] * HD + lane] = bf2pack(a0[j], a1[j]);
}

// ================= deterministic two-pass edge build (no global atomics) =================
__global__ __launch_bounds__(256) void histb2_kernel(const int* __restrict__ rows,
                                                     int* __restrict__ cnt2) {
  __shared__ int h[NB];
  int a = blockIdx.y, ch = blockIdx.x;
  for (int i = threadIdx.x; i < NB; i += 256) h[i] = 0;
  __syncthreads();
  int base = ch * EPC;
  for (int e = base + threadIdx.x; e < base + EPC; e += 256)
    atomicAdd(&h[rows[(size_t)a * NEDGE + e] >> 5], 1);
  __syncthreads();
  for (int b = threadIdx.x; b < NB; b += 256)
    cnt2[((size_t)(a * NB + b) << 6) | ch] = h[b];
}

__global__ __launch_bounds__(256) void scan1_kernel(const int* __restrict__ cnt2,
                                                    int* __restrict__ off2,
                                                    int* __restrict__ part) {
  __shared__ int sdata[256];
  int t = threadIdx.x;
  int base = blockIdx.x * 1024 + t * 4;
  int v0 = (base + 0 < M2) ? cnt2[base + 0] : 0;
  int v1 = (base + 1 < M2) ? cnt2[base + 1] : 0;
  int v2 = (base + 2 < M2) ? cnt2[base + 2] : 0;
  int v3 = (base + 3 < M2) ? cnt2[base + 3] : 0;
  int tsum = v0 + v1 + v2 + v3;
  sdata[t] = tsum;
  __syncthreads();
  for (int o = 1; o < 256; o <<= 1) {
    int x = (t >= o) ? sdata[t - o] : 0;
    __syncthreads();
    sdata[t] += x;
    __syncthreads();
  }
  int excl = sdata[t] - tsum;
  if (t == 255) part[blockIdx.x] = sdata[255];
  if (base + 0 < M2) off2[base + 0] = excl;
  if (base + 1 < M2) off2[base + 1] = excl + v0;
  if (base + 2 < M2) off2[base + 2] = excl + v0 + v1;
  if (base + 3 < M2) off2[base + 3] = excl + v0 + v1 + v2;
}

__global__ __launch_bounds__(1024) void scan2_kernel(int* __restrict__ part) {
  __shared__ int sdata[1024];
  int t = threadIdx.x;
  int v = (t < SCAN1B) ? part[t] : 0;
  sdata[t] = v;
  __syncthreads();
  for (int o = 1; o < 1024; o <<= 1) {
    int x = (t >= o) ? sdata[t - o] : 0;
    __syncthreads();
    sdata[t] += x;
    __syncthreads();
  }
  if (t < SCAN1B) part[t] = sdata[t] - v;  // exclusive
}

__global__ __launch_bounds__(256) void scan3_kernel(int* __restrict__ off2,
                                                    const int* __restrict__ part) {
  int p = part[blockIdx.x];
  int t = threadIdx.x;
#pragma unroll
  for (int j = 0; j < 4; j++) {
    int i = blockIdx.x * 1024 + j * 256 + t;
    if (i < M2) off2[i] += p;
  }
}

__global__ __launch_bounds__(256) void keyoff_kernel(const int* __restrict__ off2,
                                                     int* __restrict__ off,
                                                     int* __restrict__ cntk) {
  int k = blockIdx.x * 256 + threadIdx.x;
  if (k >= NKEY) return;
  int s = off2[(size_t)k << 6];
  int e = (k + 1 < NKEY) ? off2[(size_t)(k + 1) << 6] : (int)ME;
  off[k] = s;
  cntk[k] = e - s;
}

// pass 2: deterministic scatter of packed (lr|col,val) using LDS cursors
__global__ __launch_bounds__(256) void scatterd_kernel(
    const int* __restrict__ rows, const int* __restrict__ cols, const float* __restrict__ vals,
    const int* __restrict__ off2, int2* __restrict__ epk) {
  __shared__ int cur[NB];
  int a = blockIdx.y, ch = blockIdx.x;
  for (int b = threadIdx.x; b < NB; b += 256)
    cur[b] = off2[((size_t)(a * NB + b) << 6) | ch];
  __syncthreads();
  int base = ch * EPC;
  for (int e = base + threadIdx.x; e < base + EPC; e += 256) {
    size_t idx = (size_t)a * NEDGE + e;
    int r = rows[idx];
    int pos = atomicAdd(&cur[r >> 5], 1);
    epk[pos] = make_int2(((r & 31) << 17) | cols[idx], __float_as_int(vals[idx]));
  }
}

// pack: per bucket, coalesced read epk region, counting-sort by local row in LDS,
// write back sorted + rofftab
__global__ __launch_bounds__(256) void pack_kernel(
    const int* __restrict__ off, const int* __restrict__ cnt,
    int2* __restrict__ epk, int* __restrict__ rofftab) {
  __shared__ int smeta[CAP];
  __shared__ float sval[CAP];
  __shared__ int h[RB], hc[RB];
  int key = blockIdx.x;
  int base = off[key], n = cnt[key];
  int t = threadIdx.x, wv = t >> 6, lane = t & 63;
  if (t < RB) h[t] = 0;
  __syncthreads();
  if (n <= CAP) {
    int lm[4]; float lv[4];
    int cl = 0;
#pragma unroll
    for (int j = 0; j < 4; j++) {
      int i = t + j * 256;
      if (i < n) {
        int2 p = epk[base + i];
        lm[cl] = p.x;
        lv[cl] = __int_as_float(p.y);
        cl++;
        atomicAdd(&h[p.x >> 17], 1);
      }
    }
    __syncthreads();
    if (wv == 0) {
      int v = (lane < RB) ? h[lane] : 0;
      int incl = v;
#pragma unroll
      for (int o = 1; o < RB; o <<= 1) {
        int x = __shfl_up(incl, o, 64);
        if (lane >= o) incl += x;
      }
      if (lane < RB) {
        int excl = incl - v;
        hc[lane] = excl;
        rofftab[(size_t)key * RB + lane] = excl;
      }
    }
    __syncthreads();
    for (int j = 0; j < cl; j++) {
      int p = atomicAdd(&hc[lm[j] >> 17], 1);
      smeta[p] = lm[j];
      sval[p] = lv[j];
    }
    __syncthreads();
    for (int i = t; i < n; i += 256)
      epk[base + i] = make_int2(smeta[i], __float_as_int(sval[i]));
  }
  // n > CAP: leave unsorted; stages use slow scan path (never expected)
}

// ================= SpMM stages: sorted epk, one-shot LDS staging, deep ILP =====

// stage 1: gather xpb (bf16 x0,x1); write spb(bf16 s1,t1), cres, cz0, cz1
__global__ __launch_bounds__(256) void st1_kernel(
    const int* __restrict__ off, const int* __restrict__ cnt,
    const int* __restrict__ rofftab, const int2* __restrict__ epk,
    const unsigned int* __restrict__ xpb, const float* __restrict__ wc,
    unsigned int* __restrict__ spb, float* __restrict__ cres,
    float* __restrict__ cz0, float* __restrict__ cz1) {
  __shared__ int scol[4 * CAP2];
  __shared__ float sv[4 * CAP2];
  __shared__ int ro[4][RB + 1];
  int b = blockIdx.x, t = threadIdx.x;
  int wv = t >> 6, lane = t & 63;
  float w_s1[4], w_res[4], w_z0[4], w_t1[4], w_z1[4];
#pragma unroll
  for (int a = 0; a < 4; a++) {
    w_s1[a]  = (a < 3) ? wc[a] : 0.f;
    w_res[a] = wc[6 + a];
    w_z0[a]  = (a == 3) ? wc[14] : ((a < 2) ? wc[12 + a] : 0.f);
    w_t1[a]  = (a < 3) ? wc[18 + a] : 0.f;
    w_z1[a]  = (a == 3) ? wc[25] : ((a < 2) ? wc[23 + a] : 0.f);
  }
  int nA[4], baseA[4];
  bool fits = true;
#pragma unroll
  for (int a = 0; a < 4; a++) {
    int key = a * NB + b;
    baseA[a] = off[key];
    nA[a] = cnt[key];
    if (nA[a] > CAP2) fits = false;
  }
  float as1[8], at1[8], ares[8], az0[8], az1[8];
#pragma unroll
  for (int r = 0; r < 8; r++) { as1[r] = 0.f; at1[r] = 0.f; ares[r] = 0.f; az0[r] = 0.f; az1[r] = 0.f; }
  if (fits) {
#pragma unroll
    for (int a = 0; a < 4; a++) {
      int n = nA[a], base = baseA[a];
      for (int i = t; i < n; i += 256) {
        int2 p = epk[base + i];
        scol[a * CAP2 + i] = p.x & 0x1FFFF;
        sv[a * CAP2 + i] = __int_as_float(p.y);
      }
    }
    if (t < 4 * (RB + 1)) {
      int a = t / (RB + 1), r = t % (RB + 1);
      ro[a][r] = (r < RB) ? rofftab[(size_t)(a * NB + b) * RB + r] : nA[a];
    }
    __syncthreads();
#pragma unroll
    for (int r8 = 0; r8 < 8; r8++) {
      int r = wv * 8 + r8;
#pragma unroll
      for (int a = 0; a < 4; a++) {
        int s0 = ro[a][r], e0 = ro[a][r + 1];
        int lb = a * CAP2;
        float acc0 = 0.f, acc1 = 0.f, tc0 = 0.f, tc1 = 0.f;
        int i = s0;
        for (; i + 3 < e0; i += 4) {
          int c0 = scol[lb + i], c1 = scol[lb + i + 1];
          int c2 = scol[lb + i + 2], c3 = scol[lb + i + 3];
          float v0 = sv[lb + i], v1 = sv[lb + i + 1];
          float v2 = sv[lb + i + 2], v3 = sv[lb + i + 3];
          unsigned int g0 = xpb[(size_t)c0 * 64 + lane];
          unsigned int g1 = xpb[(size_t)c1 * 64 + lane];
          unsigned int g2 = xpb[(size_t)c2 * 64 + lane];
          unsigned int g3 = xpb[(size_t)c3 * 64 + lane];
          acc0 = fmaf(v0, bf_lo(g0), acc0); tc0 = fmaf(v0, bf_hi(g0), tc0);
          acc1 = fmaf(v1, bf_lo(g1), acc1); tc1 = fmaf(v1, bf_hi(g1), tc1);
          acc0 = fmaf(v2, bf_lo(g2), acc0); tc0 = fmaf(v2, bf_hi(g2), tc0);
          acc1 = fmaf(v3, bf_lo(g3), acc1); tc1 = fmaf(v3, bf_hi(g3), tc1);
        }
        for (; i < e0; i++) {
          unsigned int g0 = xpb[(size_t)scol[lb + i] * 64 + lane];
          float v0 = sv[lb + i];
          acc0 = fmaf(v0, bf_lo(g0), acc0); tc0 = fmaf(v0, bf_hi(g0), tc0);
        }
        float accs = acc0 + acc1, acct = tc0 + tc1;
        as1[r8]  = fmaf(w_s1[a], accs, as1[r8]);
        ares[r8] = fmaf(w_res[a], accs, ares[r8]);
        az0[r8]  = fmaf(w_z0[a], accs, az0[r8]);
        at1[r8]  = fmaf(w_t1[a], acct, at1[r8]);
        az1[r8]  = fmaf(w_z1[a], acct, az1[r8]);
      }
    }
  } else {
    // slow scan (never expected)
    for (int a = 0; a < 4; a++) {
      int base = baseA[a], n = nA[a];
      for (int i = 0; i < n; i++) {
        int2 p = epk[base + i];
        int lr = p.x >> 17, c = p.x & 0x1FFFF;
        float v = __int_as_float(p.y);
        unsigned int g = xpb[(size_t)c * 64 + lane];
        float gs = v * bf_lo(g), gt = v * bf_hi(g);
#pragma unroll
        for (int r8 = 0; r8 < 8; r8++) {
          if (lr == wv * 8 + r8) {
            as1[r8]  = fmaf(w_s1[a], gs, as1[r8]);
            ares[r8] = fmaf(w_res[a], gs, ares[r8]);
            az0[r8]  = fmaf(w_z0[a], gs, az0[r8]);
            at1[r8]  = fmaf(w_t1[a], gt, at1[r8]);
            az1[r8]  = fmaf(w_z1[a], gt, az1[r8]);
          }
        }
      }
    }
  }
  int rowbase = b * RB + wv * 8;
#pragma unroll
  for (int r8 = 0; r8 < 8; r8++) {
    size_t o = (size_t)(rowbase + r8) * 64 + lane;
    spb[o] = bf2pack(as1[r8], at1[r8]);
    cres[o] = ares[r8];
    cz0[o] = az0[r8];
    cz1[o] = az1[r8];
  }
}

// stage 2: gather spb (bf16 s1,t1); add into cres (s2 seq)+emit s2b, cz0, cz1
__global__ __launch_bounds__(256) void st2_kernel(
    const int* __restrict__ off, const int* __restrict__ cnt,
    const int* __restrict__ rofftab, const int2* __restrict__ epk,
    const unsigned int* __restrict__ spb, const float* __restrict__ wc,
    float* __restrict__ cres, unsigned short* __restrict__ s2b,
    float* __restrict__ cz0, float* __restrict__ cz1) {
  __shared__ int scol[4 * CAP2];
  __shared__ float sv[4 * CAP2];
  __shared__ int ro[4][RB + 1];
  int b = blockIdx.x, t = threadIdx.x;
  int wv = t >> 6, lane = t & 63;
  float w_seq[4], w_z0[4], w_z1[4];
#pragma unroll
  for (int a = 0; a < 4; a++) {
    w_seq[a] = (a < 3) ? wc[3 + a] : 0.f;
    w_z0[a]  = (a == 3) ? wc[17] : ((a < 2) ? wc[15 + a] : 0.f);
    w_z1[a]  = (a < 2) ? wc[21 + a] : 0.f;
  }
  int nA[4], baseA[4];
  bool fits = true;
#pragma unroll
  for (int a = 0; a < 4; a++) {
    int key = a * NB + b;
    baseA[a] = off[key];
    nA[a] = cnt[key];
    if (nA[a] > CAP2) fits = false;
  }
  float dres[8], dz0[8], dz1[8];
#pragma unroll
  for (int r = 0; r < 8; r++) { dres[r] = 0.f; dz0[r] = 0.f; dz1[r] = 0.f; }
  if (fits) {
#pragma unroll
    for (int a = 0; a < 4; a++) {
      int n = nA[a], base = baseA[a];
      for (int i = t; i < n; i += 256) {
        int2 p = epk[base + i];
        scol[a * CAP2 + i] = p.x & 0x1FFFF;
        sv[a * CAP2 + i] = __int_as_float(p.y);
      }
    }
    if (t < 4 * (RB + 1)) {
      int a = t / (RB + 1), r = t % (RB + 1);
      ro[a][r] = (r < RB) ? rofftab[(size_t)(a * NB + b) * RB + r] : nA[a];
    }
    __syncthreads();
#pragma unroll
    for (int r8 = 0; r8 < 8; r8++) {
      int r = wv * 8 + r8;
#pragma unroll
      for (int a = 0; a < 4; a++) {
        int s0 = ro[a][r], e0 = ro[a][r + 1];
        int lb = a * CAP2;
        float acc0 = 0.f, acc1 = 0.f, tc0 = 0.f, tc1 = 0.f;
        int i = s0;
        for (; i + 3 < e0; i += 4) {
          int c0 = scol[lb + i], c1 = scol[lb + i + 1];
          int c2 = scol[lb + i + 2], c3 = scol[lb + i + 3];
          float v0 = sv[lb + i], v1 = sv[lb + i + 1];
          float v2 = sv[lb + i + 2], v3 = sv[lb + i + 3];
          unsigned int g0 = spb[(size_t)c0 * 64 + lane];
          unsigned int g1 = spb[(size_t)c1 * 64 + lane];
          unsigned int g2 = spb[(size_t)c2 * 64 + lane];
          unsigned int g3 = spb[(size_t)c3 * 64 + lane];
          acc0 = fmaf(v0, bf_lo(g0), acc0); tc0 = fmaf(v0, bf_hi(g0), tc0);
          acc1 = fmaf(v1, bf_lo(g1), acc1); tc1 = fmaf(v1, bf_hi(g1), tc1);
          acc0 = fmaf(v2, bf_lo(g2), acc0); tc0 = fmaf(v2, bf_hi(g2), tc0);
          acc1 = fmaf(v3, bf_lo(g3), acc1); tc1 = fmaf(v3, bf_hi(g3), tc1);
        }
        for (; i < e0; i++) {
          unsigned int g0 = spb[(size_t)scol[lb + i] * 64 + lane];
          float v0 = sv[lb + i];
          acc0 = fmaf(v0, bf_lo(g0), acc0); tc0 = fmaf(v0, bf_hi(g0), tc0);
        }
        float accs = acc0 + acc1, acct = tc0 + tc1;
        dres[r8] = fmaf(w_seq[a], accs, dres[r8]);
        dz0[r8]  = fmaf(w_z0[a], accs, dz0[r8]);
        dz1[r8]  = fmaf(w_z1[a], acct, dz1[r8]);
      }
    }
  } else {
    for (int a = 0; a < 4; a++) {
      int base = baseA[a], n = nA[a];
      for (int i = 0; i < n; i++) {
        int2 p = epk[base + i];
        int lr = p.x >> 17, c = p.x & 0x1FFFF;
        float v = __int_as_float(p.y);
        unsigned int g = spb[(size_t)c * 64 + lane];
        float gs = v * bf_lo(g), gt = v * bf_hi(g);
#pragma unroll
        for (int r8 = 0; r8 < 8; r8++) {
          if (lr == wv * 8 + r8) {
            dres[r8] = fmaf(w_seq[a], gs, dres[r8]);
            dz0[r8]  = fmaf(w_z0[a], gs, dz0[r8]);
            dz1[r8]  = fmaf(w_z1[a], gt, dz1[r8]);
          }
        }
      }
    }
  }
  int rowbase = b * RB + wv * 8;
#pragma unroll
  for (int r8 = 0; r8 < 8; r8++) {
    size_t o = (size_t)(rowbase + r8) * 64 + lane;
    float s2v = cres[o] + dres[r8];
    cres[o] = s2v;
    s2b[o] = bf1(s2v);
    cz0[o] += dz0[r8];
    cz1[o] += dz1[r8];
  }
}

// stage 3: gather s2b (bf16) on adjs 0,1 (weight folded); add into cz0
__global__ __launch_bounds__(256) void st3_kernel(
    const int* __restrict__ off, const int* __restrict__ cnt,
    const int* __restrict__ rofftab, const int2* __restrict__ epk,
    const unsigned short* __restrict__ s2b, const float* __restrict__ wc,
    float* __restrict__ cz0) {
  __shared__ int scol[2 * CAP2];
  __shared__ float sv[2 * CAP2];
  __shared__ int ro[2][RB + 1];
  int b = blockIdx.x, t = threadIdx.x;
  int wv = t >> 6, lane = t & 63;
  float wA[2] = {wc[10], wc[11]};
  int nA[2], baseA[2];
  bool fits = true;
#pragma unroll
  for (int a = 0; a < 2; a++) {
    int key = a * NB + b;
    baseA[a] = off[key];
    nA[a] = cnt[key];
    if (nA[a] > CAP2) fits = false;
  }
  float dz[8];
#pragma unroll
  for (int r = 0; r < 8; r++) dz[r] = 0.f;
  if (fits) {
#pragma unroll
    for (int a = 0; a < 2; a++) {
      int n = nA[a], base = baseA[a];
      for (int i = t; i < n; i += 256) {
        int2 p = epk[base + i];
        scol[a * CAP2 + i] = p.x & 0x1FFFF;
        sv[a * CAP2 + i] = __int_as_float(p.y);
      }
    }
    if (t < 2 * (RB + 1)) {
      int a = t / (RB + 1), r = t % (RB + 1);
      ro[a][r] = (r < RB) ? rofftab[(size_t)(a * NB + b) * RB + r] : nA[a];
    }
    __syncthreads();
#pragma unroll
    for (int r8 = 0; r8 < 8; r8++) {
      int r = wv * 8 + r8;
#pragma unroll
      for (int a = 0; a < 2; a++) {
        int s0 = ro[a][r], e0 = ro[a][r + 1];
        int lb = a * CAP2;
        float acc0 = 0.f, acc1 = 0.f;
        int i = s0;
        for (; i + 3 < e0; i += 4) {
          float g0 = bf_s(s2b[(size_t)scol[lb + i] * 64 + lane]);
          float g1 = bf_s(s2b[(size_t)scol[lb + i + 1] * 64 + lane]);
          float g2 = bf_s(s2b[(size_t)scol[lb + i + 2] * 64 + lane]);
          float g3 = bf_s(s2b[(size_t)scol[lb + i + 3] * 64 + lane]);
          acc0 = fmaf(sv[lb + i], g0, acc0);
          acc1 = fmaf(sv[lb + i + 1], g1, acc1);
          acc0 = fmaf(sv[lb + i + 2], g2, acc0);
          acc1 = fmaf(sv[lb + i + 3], g3, acc1);
        }
        for (; i < e0; i++)
          acc0 = fmaf(sv[lb + i], bf_s(s2b[(size_t)scol[lb + i] * 64 + lane]), acc0);
        dz[r8] = fmaf(wA[a], acc0 + acc1, dz[r8]);
      }
    }
  } else {
    for (int a = 0; a < 2; a++) {
      int base = baseA[a], n = nA[a];
      for (int i = 0; i < n; i++) {
        int2 p = epk[base + i];
        int lr = p.x >> 17, c = p.x & 0x1FFFF;
        float v = __int_as_float(p.y);
        float gs = v * bf_s(s2b[(size_t)c * 64 + lane]);
#pragma unroll
        for (int r8 = 0; r8 < 8; r8++) {
          if (lr == wv * 8 + r8) dz[r8] = fmaf(wA[a], gs, dz[r8]);
        }
      }
    }
  }
  int rowbase = b * RB + wv * 8;
#pragma unroll
  for (int r8 = 0; r8 < 8; r8++) {
    size_t o = (size_t)(rowbase + r8) * 64 + lane;
    cz0[o] += dz[r8];
  }
}

// ---------------- final: LN+gelu both cells, semantic attention, classifier ----------------
__global__ __launch_bounds__(256) void final_kernel(
    const float* __restrict__ cz0, const float* __restrict__ cz1,
    const float* __restrict__ attn1_W, const float* __restrict__ attn1_b,
    const float* __restrict__ attn2_W, const float* __restrict__ attn2_b,
    const float* __restrict__ cls_W, const float* __restrict__ cls_b,
    float* __restrict__ out) {
  int wave = threadIdx.x >> 6, lane = threadIdx.x & 63;
  int n = blockIdx.x * 4 + wave;
  if (n >= NNODES) return;
  size_t idx = (size_t)n * HD + lane;

  float z0 = cz0[idx];
  float z1 = cz1[idx];

  float m0 = wave_bsum(z0) * (1.f / 64.f);
  float dv0 = z0 - m0;
  float var0 = wave_bsum(dv0 * dv0) * (1.f / 64.f);
  float y0 = dv0 * rsqrtf(var0 + 1e-5f);
  float g0 = 0.5f * y0 * (1.f + erff(y0 * 0.70710678118654752f));

  float m1 = wave_bsum(z1) * (1.f / 64.f);
  float dv1 = z1 - m1;
  float var1 = wave_bsum(dv1 * dv1) * (1.f / 64.f);
  float y1 = dv1 * rsqrtf(var1 + 1e-5f);
  float g1 = 0.5f * y1 * (1.f + erff(y1 * 0.70710678118654752f));

  float t0 = attn1_b[lane], t1 = attn1_b[lane];
#pragma unroll 8
  for (int j = 0; j < 64; j++) {
    float w = attn1_W[j * HD + lane];
    t0 = fmaf(__shfl(g0, j, 64), w, t0);
    t1 = fmaf(__shfl(g1, j, 64), w, t1);
  }
  t0 = tanhf(t0);
  t1 = tanhf(t1);
  float aw = attn2_W[lane];
  float a0 = wave_bsum(t0 * aw) + attn2_b[0];
  float a1 = wave_bsum(t1 * aw) + attn2_b[0];
  float mx = fmaxf(a0, a1);
  float e0 = expf(a0 - mx), e1 = expf(a1 - mx);
  float inv = 1.f / (e0 + e1);
  float p0 = e0 * inv, p1 = e1 * inv;
  float o = p0 * g0 + p1 * g1;

#pragma unroll
  for (int k = 0; k < 8; k++) {
    float s = wave_bsum(o * cls_W[lane * 8 + k]);
    if (lane == k) out[(size_t)n * 8 + k] = s + cls_b[k];
  }
}

extern "C" void kernel_launch(void* const* d_in, const int* in_sizes, int n_in,
                              void* d_out, int out_size, void* d_ws, size_t ws_size,
                              hipStream_t stream) {
  const float* node_feats   = (const float*)d_in[0];
  const int*   node_types   = (const int*)d_in[1];
  const int*   adj_rows     = (const int*)d_in[2];
  const int*   adj_cols     = (const int*)d_in[3];
  const float* adj_vals     = (const float*)d_in[4];
  const float* type_W       = (const float*)d_in[5];
  const float* type_b       = (const float*)d_in[6];
  const float* aW0          = (const float*)d_in[7];
  const float* ab0          = (const float*)d_in[8];
  const float* aW1          = (const float*)d_in[9];
  const float* ab1          = (const float*)d_in[10];
  const float* as_seq0      = (const float*)d_in[11];
  const float* as_last_seq0 = (const float*)d_in[12];
  const float* as_res0      = (const float*)d_in[13];
  const float* as_last_res0 = (const float*)d_in[14];
  const float* as_seq1      = (const float*)d_in[15];
  const float* as_last_seq1 = (const float*)d_in[16];
  const float* as_last_res1 = (const float*)d_in[17];
  const float* attn1_W      = (const float*)d_in[18];
  const float* attn1_b      = (const float*)d_in[19];
  const float* attn2_W      = (const float*)d_in[20];
  const float* attn2_b      = (const float*)d_in[21];
  const float* cls_W        = (const float*)d_in[22];
  const float* cls_b        = (const float*)d_in[23];
  float* out = (float*)d_out;
  float* ws = (float*)d_ws;

  unsigned int*  xpb  = (unsigned int*)(ws + XPB_OFF);
  unsigned int*  spb  = (unsigned int*)(ws + SPB_OFF);
  float*         cres = ws + CRES_OFF;
  float*         cz0  = ws + CZ0_OFF;
  float*         cz1  = ws + CZ1_OFF;
  unsigned short* s2b = (unsigned short*)(ws + S2B_OFF);
  int2*          epk  = (int2*)(ws + EPK_OFF);
  int*           cnt2 = (int*)(ws + CNT2_OFF);
  int*           off2 = (int*)(ws + OFF2_OFF);
  int*           part = (int*)(ws + PART_OFF);
  int*           off  = (int*)(ws + OFF_OFF);
  int*           cntk = (int*)(ws + CNTK_OFF);
  int*           roff = (int*)(ws + ROFF_OFF);
  int*           ncnt = (int*)(ws + NCNT_OFF);
  int*           noff = (int*)(ws + NOFF_OFF);
  int*           nperm = (int*)(ws + NPERM_OFF);
  float*         wc   = ws + WC_OFF;

  wcoef_kernel<<<1, 64, 0, stream>>>(as_seq0, as_last_seq0, as_res0, as_last_res0,
                                     as_seq1, as_last_seq1, as_last_res1, wc);

  // node type sort + typed projection (8 same-type nodes per wave)
  nhist_kernel<<<NCH, 256, 0, stream>>>(node_types, ncnt);
  nscan_kernel<<<1, 256, 0, stream>>>(ncnt, noff);
  nscatter_kernel<<<NCH, 256, 0, stream>>>(node_types, noff, nperm);
  hid2_kernel<<<NNODES / 32, 256, 0, stream>>>(node_feats, node_types, nperm,
                                               type_W, type_b, aW0, ab0, aW1, ab1, xpb);

  // deterministic edge build: hist2 -> scan -> keyoff -> LDS-cursor scatter -> pack+sort
  histb2_kernel<<<dim3(CHK, 4), 256, 0, stream>>>(adj_rows, cnt2);
  scan1_kernel<<<SCAN1B, 256, 0, stream>>>(cnt2, off2, part);
  scan2_kernel<<<1, 1024, 0, stream>>>(part);
  scan3_kernel<<<SCAN1B, 256, 0, stream>>>(off2, part);
  keyoff_kernel<<<(NKEY + 255) / 256, 256, 0, stream>>>(off2, off, cntk);
  scatterd_kernel<<<dim3(CHK, 4), 256, 0, stream>>>(adj_rows, adj_cols, adj_vals, off2, epk);
  pack_kernel<<<NKEY, 256, 0, stream>>>(off, cntk, epk, roff);

  // SpMM stages: pre-sorted edges, one-shot staging, deep-ILP gather loops
  st1_kernel<<<NB, 256, 0, stream>>>(off, cntk, roff, epk, xpb, wc, spb, cres, cz0, cz1);
  st2_kernel<<<NB, 256, 0, stream>>>(off, cntk, roff, epk, spb, wc, cres, s2b, cz0, cz1);
  st3_kernel<<<NB, 256, 0, stream>>>(off, cntk, roff, epk, s2b, wc, cz0);

  final_kernel<<<NNODES / 4, 256, 0, stream>>>(cz0, cz1,
                                               attn1_W, attn1_b, attn2_W, attn2_b,
                                               cls_W, cls_b, out);
}